// Round 3
// baseline (1087.087 us; speedup 1.0000x reference)
//
#include <hip/hip_runtime.h>
#include <cstdint>
#include <cstddef>

static constexpr int IN_F = 128;
static constexpr int HID  = 256;
#define EPS_BN 1e-5f
#define EPS_L2 1e-12f

// ---------------- CSR build ----------------

__global__ void k_deg(const int* __restrict__ dst, int E, int* __restrict__ deg){
    int i = blockIdx.x*256 + threadIdx.x;
    if (i < E) atomicAdd(&deg[dst[i]], 1);
}

__global__ void k_scanA(const int* __restrict__ deg, int N,
                        int* __restrict__ incl, int* __restrict__ bsums){
    __shared__ int lds[1024];
    int i = blockIdx.x*1024 + threadIdx.x;
    int v = (i < N) ? deg[i] : 0;
    lds[threadIdx.x] = v;
    __syncthreads();
    for (int off = 1; off < 1024; off <<= 1){
        int t = (threadIdx.x >= off) ? lds[threadIdx.x - off] : 0;
        __syncthreads();
        lds[threadIdx.x] += t;
        __syncthreads();
    }
    if (i < N) incl[i] = lds[threadIdx.x];
    if (threadIdx.x == 1023) bsums[blockIdx.x] = lds[1023];
}

__global__ void k_scanB(const int* __restrict__ bsums, int nb, int* __restrict__ ebs){
    __shared__ int lds[1024];
    int t = threadIdx.x;
    int v = (t < nb) ? bsums[t] : 0;
    lds[t] = v;
    __syncthreads();
    for (int off = 1; off < 1024; off <<= 1){
        int u = (t >= off) ? lds[t - off] : 0;
        __syncthreads();
        lds[t] += u;
        __syncthreads();
    }
    ebs[t] = lds[t] - v;   // exclusive
}

__global__ void k_scanC(const int* __restrict__ incl, const int* __restrict__ ebs,
                        int N, int* __restrict__ rowptr){
    int i = blockIdx.x*256 + threadIdx.x;
    if (i < N) rowptr[i+1] = incl[i] + ebs[i >> 10];
    if (i == 0) rowptr[0] = 0;
}

__global__ void k_scatter(const int* __restrict__ src, const int* __restrict__ dst, int E,
                          const int* __restrict__ rowptr, int* __restrict__ fill,
                          int* __restrict__ esrc){
    int i = blockIdx.x*256 + threadIdx.x;
    if (i < E){
        int d = dst[i];
        int pos = rowptr[d] + atomicAdd(&fill[d], 1);
        esrc[pos] = src[i];
    }
}

// ---------------- mean aggregation (CSR gather) ----------------

template<int F>
__global__ void k_agg(const float* __restrict__ feat, const int* __restrict__ rowptr,
                      const int* __restrict__ esrc, float* __restrict__ mean){
    int n = blockIdx.x;
    int f = threadIdx.x;          // blockDim == F
    int s = rowptr[n], e = rowptr[n+1];
    float acc = 0.f;
    for (int j = s; j < e; ++j){
        int u = esrc[j];
        acc += feat[(size_t)u*F + f];
    }
    float c = (float)(e - s);
    mean[(size_t)n*F + f] = acc / fmaxf(c, 1.0f);
}

// ---------------- fused dual GEMM: out = A1@W1 + A2@W2 + bias (+BN+ReLU) ----------------
// A1,A2: [N,K] row-major; W1,W2: [K,256] row-major. Block tile 64 rows x 64 cols,
// 256 threads, 4x4 microtile. grid = (ceil(N/64), 4).

template<int K, bool BNRELU>
__global__ __launch_bounds__(256) void k_gemm(
    const float* __restrict__ A1, const float* __restrict__ A2,
    const float* __restrict__ W1, const float* __restrict__ W2,
    const float* __restrict__ bias,
    const float* __restrict__ bng, const float* __restrict__ bnb,
    const float* __restrict__ bnm, const float* __restrict__ bnv,
    int N, float* __restrict__ out)
{
    __shared__ float xs[32][68];   // A-tile transposed: xs[k][row], pad 68 keeps 16B align
    __shared__ float wl[32][64];   // W-tile: wl[k][col]
    const int t   = threadIdx.x;
    const int m0  = blockIdx.x * 64;
    const int c0  = blockIdx.y * 64;
    const int tr4 = (t >> 4) * 4;  // row offset within tile, 0..60
    const int tc4 = (t & 15) * 4;  // col offset within tile, 0..60

    float acc[4][4] = {};

    for (int p = 0; p < 2; ++p){
        const float* __restrict__ A = p ? A2 : A1;
        const float* __restrict__ W = p ? W2 : W1;
        for (int k0 = 0; k0 < K; k0 += 32){
            __syncthreads();
            // stage A tile: 64 rows x 32 k (2048 floats), transposed into xs
            #pragma unroll
            for (int it = 0; it < 2; ++it){
                int s2  = t + it*256;        // 512 float4 slots
                int row = s2 >> 3;           // 0..63
                int kk4 = (s2 & 7) * 4;      // 0,4,..,28
                float4 v = make_float4(0.f,0.f,0.f,0.f);
                int gr = m0 + row;
                if (gr < N) v = *(const float4*)&A[(size_t)gr*K + k0 + kk4];
                xs[kk4+0][row] = v.x; xs[kk4+1][row] = v.y;
                xs[kk4+2][row] = v.z; xs[kk4+3][row] = v.w;
            }
            // stage W tile: 32 k x 64 cols (2048 floats)
            #pragma unroll
            for (int it = 0; it < 2; ++it){
                int s2 = t + it*256;
                int kk = s2 >> 4;            // 0..31
                int c4 = (s2 & 15) * 4;      // 0..60
                float4 v = *(const float4*)&W[(size_t)(k0+kk)*256 + c0 + c4];
                *(float4*)&wl[kk][c4] = v;
            }
            __syncthreads();
            #pragma unroll
            for (int kk = 0; kk < 32; ++kk){
                float4 a = *(const float4*)&xs[kk][tr4];
                float4 b = *(const float4*)&wl[kk][tc4];
                acc[0][0] += a.x*b.x; acc[0][1] += a.x*b.y; acc[0][2] += a.x*b.z; acc[0][3] += a.x*b.w;
                acc[1][0] += a.y*b.x; acc[1][1] += a.y*b.y; acc[1][2] += a.y*b.z; acc[1][3] += a.y*b.w;
                acc[2][0] += a.z*b.x; acc[2][1] += a.z*b.y; acc[2][2] += a.z*b.z; acc[2][3] += a.z*b.w;
                acc[3][0] += a.w*b.x; acc[3][1] += a.w*b.y; acc[3][2] += a.w*b.z; acc[3][3] += a.w*b.w;
            }
        }
    }

    const int c = c0 + tc4;
    float4 bs = *(const float4*)&bias[c];
    float gx[4] = {bs.x, bs.y, bs.z, bs.w};

    float g4[4], e4[4], m4[4], r4[4];
    if (BNRELU){
        float4 g = *(const float4*)&bng[c];
        float4 b = *(const float4*)&bnb[c];
        float4 m = *(const float4*)&bnm[c];
        float4 v = *(const float4*)&bnv[c];
        g4[0]=g.x; g4[1]=g.y; g4[2]=g.z; g4[3]=g.w;
        e4[0]=b.x; e4[1]=b.y; e4[2]=b.z; e4[3]=b.w;
        m4[0]=m.x; m4[1]=m.y; m4[2]=m.z; m4[3]=m.w;
        r4[0]=rsqrtf(v.x+EPS_BN); r4[1]=rsqrtf(v.y+EPS_BN);
        r4[2]=rsqrtf(v.z+EPS_BN); r4[3]=rsqrtf(v.w+EPS_BN);
    }

    #pragma unroll
    for (int i = 0; i < 4; ++i){
        int gr = m0 + tr4 + i;
        if (gr >= N) continue;
        float o[4];
        #pragma unroll
        for (int j = 0; j < 4; ++j){
            float h = acc[i][j] + gx[j];
            if (BNRELU){
                h = g4[j]*(h - m4[j])*r4[j] + e4[j];
                h = fmaxf(h, 0.f);
            }
            o[j] = h;
        }
        *(float4*)&out[(size_t)gr*256 + c] = make_float4(o[0],o[1],o[2],o[3]);
    }
}

// ---------------- in-place row L2 normalize ----------------

__global__ __launch_bounds__(256) void k_l2norm(float* __restrict__ out, int N){
    int n = blockIdx.x;
    int t = threadIdx.x;
    float v = out[(size_t)n*256 + t];
    float s = v*v;
    #pragma unroll
    for (int off = 32; off; off >>= 1) s += __shfl_xor(s, off, 64);
    __shared__ float ws[4];
    if ((t & 63) == 0) ws[t >> 6] = s;
    __syncthreads();
    s = ws[0] + ws[1] + ws[2] + ws[3];
    float nrm = fmaxf(sqrtf(s), EPS_L2);
    out[(size_t)n*256 + t] = v / nrm;
}

// ---------------- launch ----------------

extern "C" void kernel_launch(void* const* d_in, const int* in_sizes, int n_in,
                              void* d_out, int out_size, void* d_ws, size_t ws_size,
                              hipStream_t stream){
    const float* x   = (const float*)d_in[0];
    const int*   ei  = (const int*)  d_in[1];
    const float* W1l = (const float*)d_in[2];
    const float* b1l = (const float*)d_in[3];
    const float* W1r = (const float*)d_in[4];
    const float* bng = (const float*)d_in[5];
    const float* bnb = (const float*)d_in[6];
    const float* bnm = (const float*)d_in[7];
    const float* bnv = (const float*)d_in[8];
    const float* W2l = (const float*)d_in[9];
    const float* b2l = (const float*)d_in[10];
    const float* W2r = (const float*)d_in[11];
    float* out = (float*)d_out;

    const int N = in_sizes[0] / IN_F;
    const int E = in_sizes[1] / 2;
    const int* src = ei;
    const int* dst = ei + E;

    char* w = (char*)d_ws;
    auto alloc = [&](size_t bytes)->char*{
        char* p = w; w += (bytes + 255) & ~(size_t)255; return p;
    };
    int*   deg    = (int*)  alloc((size_t)N*4);
    int*   fill   = (int*)  alloc((size_t)N*4);
    int*   incl   = (int*)  alloc((size_t)N*4);
    int*   rowptr = (int*)  alloc((size_t)(N+1)*4);
    int*   bsums  = (int*)  alloc(1024*4);
    int*   ebs    = (int*)  alloc(1024*4);
    int*   esrc   = (int*)  alloc((size_t)E*4);
    float* meanbuf= (float*)alloc((size_t)N*HID*4);  // mean1 (N*128) then mean2 (N*256)
    float* h      = (float*)alloc((size_t)N*HID*4);

    hipMemsetAsync(deg,  0, (size_t)N*4, stream);
    hipMemsetAsync(fill, 0, (size_t)N*4, stream);

    const int eb = (E + 255) / 256;
    const int nb = (N + 1023) / 1024;

    k_deg    <<<eb, 256, 0, stream>>>(dst, E, deg);
    k_scanA  <<<nb, 1024, 0, stream>>>(deg, N, incl, bsums);
    k_scanB  <<<1, 1024, 0, stream>>>(bsums, nb, ebs);
    k_scanC  <<<(N+255)/256, 256, 0, stream>>>(incl, ebs, N, rowptr);
    k_scatter<<<eb, 256, 0, stream>>>(src, dst, E, rowptr, fill, esrc);

    k_agg<IN_F><<<N, IN_F, 0, stream>>>(x, rowptr, esrc, meanbuf);

    dim3 g1((N + 63) / 64, 4);
    k_gemm<IN_F, true ><<<g1, 256, 0, stream>>>(meanbuf, x, W1l, W1r, b1l,
                                                bng, bnb, bnm, bnv, N, h);

    k_agg<HID><<<N, HID, 0, stream>>>(h, rowptr, esrc, meanbuf);

    k_gemm<HID, false><<<g1, 256, 0, stream>>>(meanbuf, h, W2l, W2r, b2l,
                                               nullptr, nullptr, nullptr, nullptr, N, out);

    k_l2norm<<<N, 256, 0, stream>>>(out, N);
}

// Round 4
// 828.820 us; speedup vs baseline: 1.3116x; 1.3116x over previous
//
#include <hip/hip_runtime.h>
#include <cstdint>
#include <cstddef>

typedef unsigned short u16;
typedef __attribute__((ext_vector_type(8))) short short8;
typedef __attribute__((ext_vector_type(4))) float f32x4;

static constexpr int IN_F = 128;
static constexpr int HID  = 256;
#define EPS_BN 1e-5f
#define EPS_L2 1e-12f

// split f32 into bf16 hi + bf16 lo (truncation split; residual ~2^-15 rel)
__device__ inline void bsplit(float v, u16& h, u16& l){
    unsigned uh = __float_as_uint(v);
    h = (u16)(uh >> 16);
    float fh = __uint_as_float(uh & 0xffff0000u);
    float r  = v - fh;
    l = (u16)(__float_as_uint(r) >> 16);
}
__device__ inline float bf2f(u16 a){ return __uint_as_float((unsigned)a << 16); }

// ---------------- CSR build ----------------

__global__ void k_deg(const int* __restrict__ dst, int E, int* __restrict__ deg){
    int i = blockIdx.x*256 + threadIdx.x;
    if (i < E) atomicAdd(&deg[dst[i]], 1);
}

__global__ void k_scanA(const int* __restrict__ deg, int N,
                        int* __restrict__ incl, int* __restrict__ bsums){
    __shared__ int lds[1024];
    int i = blockIdx.x*1024 + threadIdx.x;
    int v = (i < N) ? deg[i] : 0;
    lds[threadIdx.x] = v;
    __syncthreads();
    for (int off = 1; off < 1024; off <<= 1){
        int t = (threadIdx.x >= off) ? lds[threadIdx.x - off] : 0;
        __syncthreads();
        lds[threadIdx.x] += t;
        __syncthreads();
    }
    if (i < N) incl[i] = lds[threadIdx.x];
    if (threadIdx.x == 1023) bsums[blockIdx.x] = lds[1023];
}

__global__ void k_scanB(const int* __restrict__ bsums, int nb, int* __restrict__ ebs){
    __shared__ int lds[1024];
    int t = threadIdx.x;
    int v = (t < nb) ? bsums[t] : 0;
    lds[t] = v;
    __syncthreads();
    for (int off = 1; off < 1024; off <<= 1){
        int u = (t >= off) ? lds[t - off] : 0;
        __syncthreads();
        lds[t] += u;
        __syncthreads();
    }
    ebs[t] = lds[t] - v;   // exclusive
}

__global__ void k_scanC(const int* __restrict__ incl, const int* __restrict__ ebs,
                        int N, int* __restrict__ rowptr){
    int i = blockIdx.x*256 + threadIdx.x;
    if (i < N) rowptr[i+1] = incl[i] + ebs[i >> 10];
    if (i == 0) rowptr[0] = 0;
}

__global__ void k_scatter(const int* __restrict__ src, const int* __restrict__ dst, int E,
                          const int* __restrict__ rowptr, int* __restrict__ fill,
                          int* __restrict__ esrc){
    int i = blockIdx.x*256 + threadIdx.x;
    if (i < E){
        int d = dst[i];
        int pos = rowptr[d] + atomicAdd(&fill[d], 1);
        esrc[pos] = src[i];
    }
}

// ---------------- input / weight split passes ----------------

__global__ void k_xsplit(const float* __restrict__ x, u16* __restrict__ xh,
                         u16* __restrict__ xl, int n4){
    int i = blockIdx.x*256 + threadIdx.x;
    if (i >= n4) return;
    float4 v = *(const float4*)&x[(size_t)i*4];
    ushort4 h, l;
    bsplit(v.x, h.x, l.x); bsplit(v.y, h.y, l.y);
    bsplit(v.z, h.z, l.z); bsplit(v.w, h.w, l.w);
    *(ushort4*)&xh[(size_t)i*4] = h;
    *(ushort4*)&xl[(size_t)i*4] = l;
}

// W [K][256] row-major f32 -> Wt planes [256][K] bf16 hi/lo
__global__ void k_wsplit(const float* __restrict__ W, u16* __restrict__ wth,
                         u16* __restrict__ wtl, int K){
    int i = blockIdx.x*256 + threadIdx.x;
    if (i >= K*256) return;
    int k = i >> 8, c = i & 255;
    u16 h, l; bsplit(W[i], h, l);
    wth[c*K + k] = h;
    wtl[c*K + k] = l;
}

// ---------------- mean aggregation (CSR gather) ----------------

// gather f32 source, emit hi/lo planes. blockDim == F
template<int F>
__global__ void k_aggf(const float* __restrict__ feat, const int* __restrict__ rowptr,
                       const int* __restrict__ esrc,
                       u16* __restrict__ mh, u16* __restrict__ ml){
    int n = blockIdx.x, f = threadIdx.x;
    int s = rowptr[n], e = rowptr[n+1];
    float acc = 0.f;
    for (int j = s; j < e; ++j)
        acc += feat[(size_t)esrc[j]*F + f];
    float mv = acc / fmaxf((float)(e - s), 1.f);
    u16 h, l; bsplit(mv, h, l);
    mh[(size_t)n*F + f] = h;
    ml[(size_t)n*F + f] = l;
}

// gather hi/lo-plane source, emit hi/lo planes. blockDim == F
template<int F>
__global__ void k_aggp(const u16* __restrict__ fh, const u16* __restrict__ fl,
                       const int* __restrict__ rowptr, const int* __restrict__ esrc,
                       u16* __restrict__ mh, u16* __restrict__ ml){
    int n = blockIdx.x, f = threadIdx.x;
    int s = rowptr[n], e = rowptr[n+1];
    float acc = 0.f;
    for (int j = s; j < e; ++j){
        size_t o = (size_t)esrc[j]*F + f;
        acc += bf2f(fh[o]) + bf2f(fl[o]);
    }
    float mv = acc / fmaxf((float)(e - s), 1.f);
    u16 h, l; bsplit(mv, h, l);
    mh[(size_t)n*F + f] = h;
    ml[(size_t)n*F + f] = l;
}

// ---------------- split-bf16 MFMA dual GEMM ----------------
// out = A1@W1 + A2@W2 (+bias, +BN/ReLU). Concat along K: nkb1+nkb2 blocks of 32 k.
// A planes: [N][sA] bf16 row-major. B planes: Wt [256][sB] bf16 (k-contiguous rows).
// Tile: 128 rows x 128 cols, 256 thr = 4 waves (2x2 of 64x64), mfma_f32_16x16x32_bf16.
// 3-term split: hi*hi + lo*hi + hi*lo (~f32 precision).
// LDS tiles [128][32] bf16 per plane as 16B chunks; slot = row*4 + (c ^ (row&3)).

template<int NKB1, int NKB2, bool BNRELU, bool WRITE_H>
__global__ __launch_bounds__(256, 2) void k_gemm(
    const u16* __restrict__ A1h, const u16* __restrict__ A1l, int sa1,
    const u16* __restrict__ A2h, const u16* __restrict__ A2l, int sa2,
    const u16* __restrict__ B1h, const u16* __restrict__ B1l, int sb1,
    const u16* __restrict__ B2h, const u16* __restrict__ B2l, int sb2,
    const float* __restrict__ bias,
    const float* __restrict__ bng, const float* __restrict__ bnb,
    const float* __restrict__ bnm, const float* __restrict__ bnv,
    int N, float* __restrict__ outf,
    u16* __restrict__ outh, u16* __restrict__ outl)
{
    __shared__ uint4 LA[1024];   // [0..511] hi plane, [512..1023] lo plane
    __shared__ uint4 LB[1024];

    const int t    = threadIdx.x;
    const int wave = t >> 6, lane = t & 63;
    const int wr   = (wave >> 1) * 64;      // wave row offset in tile
    const int wc   = (wave &  1) * 64;      // wave col offset
    const int m0   = blockIdx.y * 128;
    const int c0   = blockIdx.x * 128;

    f32x4 acc[4][4] = {};

    // staging: 512 chunks (16B) per plane tile; this thread stages chunks t and t+256
    const int r0 = t >> 2,        cc0 = t & 3;
    const int r1 = (t+256) >> 2,  cc1 = (t+256) & 3;
    const int slot0 = r0*4 + (cc0 ^ (r0 & 3));
    const int slot1 = r1*4 + (cc1 ^ (r1 & 3));
    const int ar0 = min(m0 + r0, N-1);
    const int ar1 = min(m0 + r1, N-1);

    const int NKB = NKB1 + NKB2;
    for (int kb = 0; kb < NKB; ++kb){
        const u16 *pAh, *pAl, *pBh, *pBl; int sA, sB, k0;
        if (kb < NKB1){ pAh=A1h; pAl=A1l; sA=sa1; pBh=B1h; pBl=B1l; sB=sb1; k0 = kb*32; }
        else          { pAh=A2h; pAl=A2l; sA=sa2; pBh=B2h; pBl=B2l; sB=sb2; k0 = (kb-NKB1)*32; }

        // global -> regs (issued before barrier so vmem overlaps prior compute)
        uint4 vah0 = *(const uint4*)(pAh + (size_t)ar0*sA + k0 + cc0*8);
        uint4 vah1 = *(const uint4*)(pAh + (size_t)ar1*sA + k0 + cc1*8);
        uint4 val0 = *(const uint4*)(pAl + (size_t)ar0*sA + k0 + cc0*8);
        uint4 val1 = *(const uint4*)(pAl + (size_t)ar1*sA + k0 + cc1*8);
        uint4 vbh0 = *(const uint4*)(pBh + (size_t)(c0+r0)*sB + k0 + cc0*8);
        uint4 vbh1 = *(const uint4*)(pBh + (size_t)(c0+r1)*sB + k0 + cc1*8);
        uint4 vbl0 = *(const uint4*)(pBl + (size_t)(c0+r0)*sB + k0 + cc0*8);
        uint4 vbl1 = *(const uint4*)(pBl + (size_t)(c0+r1)*sB + k0 + cc1*8);

        __syncthreads();
        LA[slot0]     = vah0;  LA[slot1]     = vah1;
        LA[512+slot0] = val0;  LA[512+slot1] = val1;
        LB[slot0]     = vbh0;  LB[slot1]     = vbh1;
        LB[512+slot0] = vbl0;  LB[512+slot1] = vbl1;
        __syncthreads();

        const int cl = lane & 15;      // row/col within 16
        const int cg = lane >> 4;      // k-chunk 0..3
        short8 bh[4], bl[4];
        #pragma unroll
        for (int n = 0; n < 4; ++n){
            int col  = wc + n*16 + cl;
            int slot = col*4 + (cg ^ (col & 3));
            bh[n] = *(const short8*)&LB[slot];
            bl[n] = *(const short8*)&LB[512+slot];
        }
        #pragma unroll
        for (int m = 0; m < 4; ++m){
            int row  = wr + m*16 + cl;
            int slot = row*4 + (cg ^ (row & 3));
            short8 ah = *(const short8*)&LA[slot];
            short8 al = *(const short8*)&LA[512+slot];
            #pragma unroll
            for (int n = 0; n < 4; ++n){
                acc[m][n] = __builtin_amdgcn_mfma_f32_16x16x32_bf16(ah, bh[n], acc[m][n], 0,0,0);
                acc[m][n] = __builtin_amdgcn_mfma_f32_16x16x32_bf16(al, bh[n], acc[m][n], 0,0,0);
                acc[m][n] = __builtin_amdgcn_mfma_f32_16x16x32_bf16(ah, bl[n], acc[m][n], 0,0,0);
            }
        }
    }

    // epilogue: C/D layout col = lane&15, row = (lane>>4)*4 + reg
    const int cl = lane & 15, rg = lane >> 4;
    #pragma unroll
    for (int n = 0; n < 4; ++n){
        int col = c0 + wc + n*16 + cl;
        float bv = bias[col];
        float g=0.f, be=0.f, mm=0.f, rv=0.f;
        if constexpr (BNRELU){
            g = bng[col]; be = bnb[col]; mm = bnm[col];
            rv = rsqrtf(bnv[col] + EPS_BN);
        }
        #pragma unroll
        for (int m = 0; m < 4; ++m){
            #pragma unroll
            for (int i = 0; i < 4; ++i){
                int row = m0 + wr + m*16 + rg*4 + i;
                if (row < N){
                    float v = acc[m][n][i] + bv;
                    if constexpr (BNRELU) v = fmaxf(g*(v - mm)*rv + be, 0.f);
                    if constexpr (WRITE_H){
                        u16 hh, hl; bsplit(v, hh, hl);
                        outh[(size_t)row*256 + col] = hh;
                        outl[(size_t)row*256 + col] = hl;
                    } else {
                        outf[(size_t)row*256 + col] = v;
                    }
                }
            }
        }
    }
}

// ---------------- in-place row L2 normalize ----------------

__global__ __launch_bounds__(256) void k_l2norm(float* __restrict__ out, int N){
    int n = blockIdx.x;
    int t = threadIdx.x;
    float v = out[(size_t)n*256 + t];
    float s = v*v;
    #pragma unroll
    for (int off = 32; off; off >>= 1) s += __shfl_xor(s, off, 64);
    __shared__ float ws[4];
    if ((t & 63) == 0) ws[t >> 6] = s;
    __syncthreads();
    s = ws[0] + ws[1] + ws[2] + ws[3];
    float nrm = fmaxf(sqrtf(s), EPS_L2);
    out[(size_t)n*256 + t] = v / nrm;
}

// ---------------- launch ----------------

extern "C" void kernel_launch(void* const* d_in, const int* in_sizes, int n_in,
                              void* d_out, int out_size, void* d_ws, size_t ws_size,
                              hipStream_t stream){
    const float* x   = (const float*)d_in[0];
    const int*   ei  = (const int*)  d_in[1];
    const float* W1l = (const float*)d_in[2];
    const float* b1l = (const float*)d_in[3];
    const float* W1r = (const float*)d_in[4];
    const float* bng = (const float*)d_in[5];
    const float* bnb = (const float*)d_in[6];
    const float* bnm = (const float*)d_in[7];
    const float* bnv = (const float*)d_in[8];
    const float* W2l = (const float*)d_in[9];
    const float* b2l = (const float*)d_in[10];
    const float* W2r = (const float*)d_in[11];
    float* out = (float*)d_out;

    const int N = in_sizes[0] / IN_F;
    const int E = in_sizes[1] / 2;
    const int* src = ei;
    const int* dst = ei + E;

    char* w = (char*)d_ws;
    auto alloc = [&](size_t bytes)->char*{
        char* p = w; w += (bytes + 255) & ~(size_t)255; return p;
    };
    int* deg    = (int*)alloc((size_t)N*4);
    int* fill   = (int*)alloc((size_t)N*4);
    int* incl   = (int*)alloc((size_t)N*4);
    int* rowptr = (int*)alloc((size_t)(N+1)*4);
    int* bsums  = (int*)alloc(1024*4);
    int* ebs    = (int*)alloc(1024*4);
    int* esrc   = (int*)alloc((size_t)E*4);
    // region R: x planes + mean1 planes (contiguous; reused as mean2 planes later)
    u16* xh  = (u16*)alloc((size_t)N*IN_F*2);   // N*128*2 bytes, 256-aligned size
    u16* xl  = (u16*)alloc((size_t)N*IN_F*2);
    u16* m1h = (u16*)alloc((size_t)N*IN_F*2);
    u16* m1l = (u16*)alloc((size_t)N*IN_F*2);
    u16* hh  = (u16*)alloc((size_t)N*HID*2);
    u16* hl  = (u16*)alloc((size_t)N*HID*2);
    u16* w1lh = (u16*)alloc((size_t)IN_F*256*2);
    u16* w1ll = (u16*)alloc((size_t)IN_F*256*2);
    u16* w1rh = (u16*)alloc((size_t)IN_F*256*2);
    u16* w1rl = (u16*)alloc((size_t)IN_F*256*2);
    u16* w2lh = (u16*)alloc((size_t)HID*256*2);
    u16* w2ll = (u16*)alloc((size_t)HID*256*2);
    u16* w2rh = (u16*)alloc((size_t)HID*256*2);
    u16* w2rl = (u16*)alloc((size_t)HID*256*2);
    // mean2 planes alias region R (x/m1 dead by then); sizes match exactly
    u16* m2h = xh;    // spans xh..xl  (N*256*2 bytes)
    u16* m2l = m1h;   // spans m1h..m1l

    hipMemsetAsync(deg,  0, (size_t)N*4, stream);
    hipMemsetAsync(fill, 0, (size_t)N*4, stream);

    const int eb = (E + 255) / 256;
    const int nb = (N + 1023) / 1024;

    k_deg    <<<eb, 256, 0, stream>>>(dst, E, deg);
    k_scanA  <<<nb, 1024, 0, stream>>>(deg, N, incl, bsums);
    k_scanB  <<<1, 1024, 0, stream>>>(bsums, nb, ebs);
    k_scanC  <<<(N+255)/256, 256, 0, stream>>>(incl, ebs, N, rowptr);
    k_scatter<<<eb, 256, 0, stream>>>(src, dst, E, rowptr, fill, esrc);

    // splits
    k_xsplit<<<((N*IN_F/4)+255)/256, 256, 0, stream>>>(x, xh, xl, N*IN_F/4);
    k_wsplit<<<(IN_F*256+255)/256, 256, 0, stream>>>(W1l, w1lh, w1ll, IN_F);
    k_wsplit<<<(IN_F*256+255)/256, 256, 0, stream>>>(W1r, w1rh, w1rl, IN_F);
    k_wsplit<<<(HID*256+255)/256, 256, 0, stream>>>(W2l, w2lh, w2ll, HID);
    k_wsplit<<<(HID*256+255)/256, 256, 0, stream>>>(W2r, w2rh, w2rl, HID);

    // layer 1
    k_aggf<IN_F><<<N, IN_F, 0, stream>>>(x, rowptr, esrc, m1h, m1l);
    dim3 g(2, (N + 127) / 128);
    k_gemm<4, 4, true, true><<<g, 256, 0, stream>>>(
        m1h, m1l, IN_F, xh, xl, IN_F,
        w1lh, w1ll, IN_F, w1rh, w1rl, IN_F,
        b1l, bng, bnb, bnm, bnv, N, nullptr, hh, hl);

    // layer 2
    k_aggp<HID><<<N, HID, 0, stream>>>(hh, hl, rowptr, esrc, m2h, m2l);
    k_gemm<8, 8, false, false><<<g, 256, 0, stream>>>(
        m2h, m2l, HID, hh, hl, HID,
        w2lh, w2ll, HID, w2rh, w2rl, HID,
        b2l, nullptr, nullptr, nullptr, nullptr, N, out, nullptr, nullptr);

    k_l2norm<<<N, 256, 0, stream>>>(out, N);
}

// Round 5
// 699.198 us; speedup vs baseline: 1.5548x; 1.1854x over previous
//
#include <hip/hip_runtime.h>
#include <cstdint>
#include <cstddef>

typedef unsigned short u16;
typedef __attribute__((ext_vector_type(8))) short short8;
typedef __attribute__((ext_vector_type(4))) float f32x4;

static constexpr int IN_F = 128;
static constexpr int HID  = 256;
#define EPS_BN 1e-5f
#define EPS_L2 1e-12f

// split f32 into bf16 hi + bf16 lo (truncation split; residual ~2^-17 rel)
__device__ inline void bsplit(float v, u16& h, u16& l){
    unsigned uh = __float_as_uint(v);
    h = (u16)(uh >> 16);
    float fh = __uint_as_float(uh & 0xffff0000u);
    float r  = v - fh;
    l = (u16)(__float_as_uint(r) >> 16);
}
__device__ inline float bf2f(u16 a){ return __uint_as_float((unsigned)a << 16); }
// f32 -> bf16 round-to-nearest-even (values here are finite, no NaN concern)
__device__ inline u16 f2bf_rne(float v){
    unsigned u = __float_as_uint(v);
    return (u16)((u + 0x7fffu + ((u >> 16) & 1u)) >> 16);
}

// ---------------- CSR build ----------------

__global__ void k_deg(const int* __restrict__ dst, int E, int* __restrict__ deg){
    int i = blockIdx.x*256 + threadIdx.x;
    if (i < E) atomicAdd(&deg[dst[i]], 1);
}

__global__ void k_scanA(const int* __restrict__ deg, int N,
                        int* __restrict__ incl, int* __restrict__ bsums){
    __shared__ int lds[1024];
    int i = blockIdx.x*1024 + threadIdx.x;
    int v = (i < N) ? deg[i] : 0;
    lds[threadIdx.x] = v;
    __syncthreads();
    for (int off = 1; off < 1024; off <<= 1){
        int t = (threadIdx.x >= off) ? lds[threadIdx.x - off] : 0;
        __syncthreads();
        lds[threadIdx.x] += t;
        __syncthreads();
    }
    if (i < N) incl[i] = lds[threadIdx.x];
    if (threadIdx.x == 1023) bsums[blockIdx.x] = lds[1023];
}

__global__ void k_scanB(const int* __restrict__ bsums, int nb, int* __restrict__ ebs){
    __shared__ int lds[1024];
    int t = threadIdx.x;
    int v = (t < nb) ? bsums[t] : 0;
    lds[t] = v;
    __syncthreads();
    for (int off = 1; off < 1024; off <<= 1){
        int u = (t >= off) ? lds[t - off] : 0;
        __syncthreads();
        lds[t] += u;
        __syncthreads();
    }
    ebs[t] = lds[t] - v;   // exclusive
}

__global__ void k_scanC(const int* __restrict__ incl, const int* __restrict__ ebs,
                        int N, int* __restrict__ rowptr){
    int i = blockIdx.x*256 + threadIdx.x;
    if (i < N) rowptr[i+1] = incl[i] + ebs[i >> 10];
    if (i == 0) rowptr[0] = 0;
}

__global__ void k_scatter(const int* __restrict__ src, const int* __restrict__ dst, int E,
                          const int* __restrict__ rowptr, int* __restrict__ fill,
                          int* __restrict__ esrc){
    int i = blockIdx.x*256 + threadIdx.x;
    if (i < E){
        int d = dst[i];
        int pos = rowptr[d] + atomicAdd(&fill[d], 1);
        esrc[pos] = src[i];
    }
}

// ---------------- input / weight split passes ----------------

__global__ void k_xsplit(const float* __restrict__ x, u16* __restrict__ xh,
                         u16* __restrict__ xl, int n4){
    int i = blockIdx.x*256 + threadIdx.x;
    if (i >= n4) return;
    float4 v = *(const float4*)&x[(size_t)i*4];
    ushort4 h, l;
    bsplit(v.x, h.x, l.x); bsplit(v.y, h.y, l.y);
    bsplit(v.z, h.z, l.z); bsplit(v.w, h.w, l.w);
    *(ushort4*)&xh[(size_t)i*4] = h;
    *(ushort4*)&xl[(size_t)i*4] = l;
}

// W [K][256] row-major f32 -> Wt planes [256][K] bf16 hi/lo
__global__ void k_wsplit(const float* __restrict__ W, u16* __restrict__ wth,
                         u16* __restrict__ wtl, int K){
    int i = blockIdx.x*256 + threadIdx.x;
    if (i >= K*256) return;
    int k = i >> 8, c = i & 255;
    u16 h, l; bsplit(W[i], h, l);
    wth[c*K + k] = h;
    wtl[c*K + k] = l;
}

// ---------------- mean aggregation (CSR gather) ----------------

// layer 1: gather f32 x, emit hi/lo planes. blockDim == F
template<int F>
__global__ void k_aggf(const float* __restrict__ feat, const int* __restrict__ rowptr,
                       const int* __restrict__ esrc,
                       u16* __restrict__ mh, u16* __restrict__ ml){
    int n = blockIdx.x, f = threadIdx.x;
    int s = rowptr[n], e = rowptr[n+1];
    float acc = 0.f;
    for (int j = s; j < e; ++j)
        acc += feat[(size_t)esrc[j]*F + f];
    float mv = acc / fmaxf((float)(e - s), 1.f);
    u16 h, l; bsplit(mv, h, l);
    mh[(size_t)n*F + f] = h;
    ml[(size_t)n*F + f] = l;
}

// layer 2: gather single-plane bf16 h, emit hi/lo mean planes.
// blockDim == F/2; each thread covers 2 features via ushort2.
template<int F>
__global__ void k_aggh(const u16* __restrict__ fh,
                       const int* __restrict__ rowptr, const int* __restrict__ esrc,
                       u16* __restrict__ mh, u16* __restrict__ ml){
    int n = blockIdx.x, t = threadIdx.x;       // t in [0, F/2)
    int s = rowptr[n], e = rowptr[n+1];
    float a0 = 0.f, a1 = 0.f;
    for (int j = s; j < e; ++j){
        ushort2 v = *(const ushort2*)&fh[(size_t)esrc[j]*F + 2*t];
        a0 += bf2f(v.x);
        a1 += bf2f(v.y);
    }
    float c = fmaxf((float)(e - s), 1.f);
    a0 /= c; a1 /= c;
    ushort2 h, l;
    bsplit(a0, h.x, l.x);
    bsplit(a1, h.y, l.y);
    *(ushort2*)&mh[(size_t)n*F + 2*t] = h;
    *(ushort2*)&ml[(size_t)n*F + 2*t] = l;
}

// ---------------- split-bf16 MFMA dual GEMM ----------------
// out = A1@W1 + A2@W2 (+bias, +BN/ReLU). Concat along K: NKB1+NKB2 blocks of 32 k.
// A1 planes always split (hi/lo); A2 split iff A2SPLIT (else single bf16 plane).
// B (weights) always split. Tile: 128x128, 256 thr = 4 waves (2x2 of 64x64),
// mfma_f32_16x16x32_bf16. LDS 16B-chunk slot = row*4 + (c ^ (row&3)).

template<int NKB1, int NKB2, bool A2SPLIT, bool BNRELU, bool WRITE_H>
__global__ __launch_bounds__(256, 2) void k_gemm(
    const u16* __restrict__ A1h, const u16* __restrict__ A1l, int sa1,
    const u16* __restrict__ A2h, const u16* __restrict__ A2l, int sa2,
    const u16* __restrict__ B1h, const u16* __restrict__ B1l, int sb1,
    const u16* __restrict__ B2h, const u16* __restrict__ B2l, int sb2,
    const float* __restrict__ bias,
    const float* __restrict__ bng, const float* __restrict__ bnb,
    const float* __restrict__ bnm, const float* __restrict__ bnv,
    int N, float* __restrict__ outf, u16* __restrict__ outh)
{
    __shared__ uint4 LA[1024];   // [0..511] hi plane, [512..1023] lo plane
    __shared__ uint4 LB[1024];

    const int t    = threadIdx.x;
    const int wave = t >> 6, lane = t & 63;
    const int wr   = (wave >> 1) * 64;
    const int wc   = (wave &  1) * 64;
    const int m0   = blockIdx.y * 128;
    const int c0   = blockIdx.x * 128;

    f32x4 acc[4][4] = {};

    const int r0 = t >> 2,        cc0 = t & 3;
    const int r1 = (t+256) >> 2,  cc1 = (t+256) & 3;
    const int slot0 = r0*4 + (cc0 ^ (r0 & 3));
    const int slot1 = r1*4 + (cc1 ^ (r1 & 3));
    const int ar0 = min(m0 + r0, N-1);
    const int ar1 = min(m0 + r1, N-1);

    const int NKB = NKB1 + NKB2;
    for (int kb = 0; kb < NKB; ++kb){
        const u16 *pAh, *pAl, *pBh, *pBl; int sA, sB, k0;
        bool asplit;
        if (kb < NKB1){ pAh=A1h; pAl=A1l; sA=sa1; pBh=B1h; pBl=B1l; sB=sb1; k0 = kb*32; asplit = true; }
        else          { pAh=A2h; pAl=A2l; sA=sa2; pBh=B2h; pBl=B2l; sB=sb2; k0 = (kb-NKB1)*32; asplit = A2SPLIT; }

        // global -> regs (issued before barrier so vmem overlaps prior compute)
        uint4 vah0 = *(const uint4*)(pAh + (size_t)ar0*sA + k0 + cc0*8);
        uint4 vah1 = *(const uint4*)(pAh + (size_t)ar1*sA + k0 + cc1*8);
        uint4 val0, val1;
        if (asplit){
            val0 = *(const uint4*)(pAl + (size_t)ar0*sA + k0 + cc0*8);
            val1 = *(const uint4*)(pAl + (size_t)ar1*sA + k0 + cc1*8);
        }
        uint4 vbh0 = *(const uint4*)(pBh + (size_t)(c0+r0)*sB + k0 + cc0*8);
        uint4 vbh1 = *(const uint4*)(pBh + (size_t)(c0+r1)*sB + k0 + cc1*8);
        uint4 vbl0 = *(const uint4*)(pBl + (size_t)(c0+r0)*sB + k0 + cc0*8);
        uint4 vbl1 = *(const uint4*)(pBl + (size_t)(c0+r1)*sB + k0 + cc1*8);

        __syncthreads();
        LA[slot0] = vah0;  LA[slot1] = vah1;
        if (asplit){ LA[512+slot0] = val0;  LA[512+slot1] = val1; }
        LB[slot0] = vbh0;  LB[slot1] = vbh1;
        LB[512+slot0] = vbl0;  LB[512+slot1] = vbl1;
        __syncthreads();

        const int cl = lane & 15;
        const int cg = lane >> 4;
        short8 bh[4], bl[4];
        #pragma unroll
        for (int n = 0; n < 4; ++n){
            int col  = wc + n*16 + cl;
            int slot = col*4 + (cg ^ (col & 3));
            bh[n] = *(const short8*)&LB[slot];
            bl[n] = *(const short8*)&LB[512+slot];
        }
        #pragma unroll
        for (int m = 0; m < 4; ++m){
            int row  = wr + m*16 + cl;
            int slot = row*4 + (cg ^ (row & 3));
            short8 ah = *(const short8*)&LA[slot];
            if (asplit){
                short8 al = *(const short8*)&LA[512+slot];
                #pragma unroll
                for (int n = 0; n < 4; ++n){
                    acc[m][n] = __builtin_amdgcn_mfma_f32_16x16x32_bf16(ah, bh[n], acc[m][n], 0,0,0);
                    acc[m][n] = __builtin_amdgcn_mfma_f32_16x16x32_bf16(al, bh[n], acc[m][n], 0,0,0);
                    acc[m][n] = __builtin_amdgcn_mfma_f32_16x16x32_bf16(ah, bl[n], acc[m][n], 0,0,0);
                }
            } else {
                #pragma unroll
                for (int n = 0; n < 4; ++n){
                    acc[m][n] = __builtin_amdgcn_mfma_f32_16x16x32_bf16(ah, bh[n], acc[m][n], 0,0,0);
                    acc[m][n] = __builtin_amdgcn_mfma_f32_16x16x32_bf16(ah, bl[n], acc[m][n], 0,0,0);
                }
            }
        }
    }

    // epilogue: C/D layout col = lane&15, row = (lane>>4)*4 + reg
    const int cl = lane & 15, rg = lane >> 4;
    #pragma unroll
    for (int n = 0; n < 4; ++n){
        int col = c0 + wc + n*16 + cl;
        float bv = bias[col];
        float g=0.f, be=0.f, mm=0.f, rv=0.f;
        if constexpr (BNRELU){
            g = bng[col]; be = bnb[col]; mm = bnm[col];
            rv = rsqrtf(bnv[col] + EPS_BN);
        }
        #pragma unroll
        for (int m = 0; m < 4; ++m){
            #pragma unroll
            for (int i = 0; i < 4; ++i){
                int row = m0 + wr + m*16 + rg*4 + i;
                if (row < N){
                    float v = acc[m][n][i] + bv;
                    if constexpr (BNRELU) v = fmaxf(g*(v - mm)*rv + be, 0.f);
                    if constexpr (WRITE_H){
                        outh[(size_t)row*256 + col] = f2bf_rne(v);
                    } else {
                        outf[(size_t)row*256 + col] = v;
                    }
                }
            }
        }
    }
}

// ---------------- in-place row L2 normalize ----------------

__global__ __launch_bounds__(256) void k_l2norm(float* __restrict__ out, int N){
    int n = blockIdx.x;
    int t = threadIdx.x;
    float v = out[(size_t)n*256 + t];
    float s = v*v;
    #pragma unroll
    for (int off = 32; off; off >>= 1) s += __shfl_xor(s, off, 64);
    __shared__ float ws[4];
    if ((t & 63) == 0) ws[t >> 6] = s;
    __syncthreads();
    s = ws[0] + ws[1] + ws[2] + ws[3];
    float nrm = fmaxf(sqrtf(s), EPS_L2);
    out[(size_t)n*256 + t] = v / nrm;
}

// ---------------- launch ----------------

extern "C" void kernel_launch(void* const* d_in, const int* in_sizes, int n_in,
                              void* d_out, int out_size, void* d_ws, size_t ws_size,
                              hipStream_t stream){
    const float* x   = (const float*)d_in[0];
    const int*   ei  = (const int*)  d_in[1];
    const float* W1l = (const float*)d_in[2];
    const float* b1l = (const float*)d_in[3];
    const float* W1r = (const float*)d_in[4];
    const float* bng = (const float*)d_in[5];
    const float* bnb = (const float*)d_in[6];
    const float* bnm = (const float*)d_in[7];
    const float* bnv = (const float*)d_in[8];
    const float* W2l = (const float*)d_in[9];
    const float* b2l = (const float*)d_in[10];
    const float* W2r = (const float*)d_in[11];
    float* out = (float*)d_out;

    const int N = in_sizes[0] / IN_F;
    const int E = in_sizes[1] / 2;
    const int* src = ei;
    const int* dst = ei + E;

    char* w = (char*)d_ws;
    auto alloc = [&](size_t bytes)->char*{
        char* p = w; w += (bytes + 255) & ~(size_t)255; return p;
    };
    int* deg    = (int*)alloc((size_t)N*4);
    int* fill   = (int*)alloc((size_t)N*4);
    int* incl   = (int*)alloc((size_t)N*4);
    int* rowptr = (int*)alloc((size_t)(N+1)*4);
    int* bsums  = (int*)alloc(1024*4);
    int* ebs    = (int*)alloc(1024*4);
    int* esrc   = (int*)alloc((size_t)E*4);
    // region R: x planes + mean1 planes (contiguous; reused as mean2 planes later)
    u16* xh  = (u16*)alloc((size_t)N*IN_F*2);   // N*128*2 bytes (exact 256-multiple)
    u16* xl  = (u16*)alloc((size_t)N*IN_F*2);
    u16* m1h = (u16*)alloc((size_t)N*IN_F*2);
    u16* m1l = (u16*)alloc((size_t)N*IN_F*2);
    u16* hh  = (u16*)alloc((size_t)N*HID*2);    // single bf16 plane for h
    u16* w1lh = (u16*)alloc((size_t)IN_F*256*2);
    u16* w1ll = (u16*)alloc((size_t)IN_F*256*2);
    u16* w1rh = (u16*)alloc((size_t)IN_F*256*2);
    u16* w1rl = (u16*)alloc((size_t)IN_F*256*2);
    u16* w2lh = (u16*)alloc((size_t)HID*256*2);
    u16* w2ll = (u16*)alloc((size_t)HID*256*2);
    u16* w2rh = (u16*)alloc((size_t)HID*256*2);
    u16* w2rl = (u16*)alloc((size_t)HID*256*2);
    // mean2 planes alias region R (x/m1 dead by then); spans are exact
    u16* m2h = xh;    // spans xh..xl  (N*256*2 bytes)
    u16* m2l = m1h;   // spans m1h..m1l

    hipMemsetAsync(deg,  0, (size_t)N*4, stream);
    hipMemsetAsync(fill, 0, (size_t)N*4, stream);

    const int eb = (E + 255) / 256;
    const int nb = (N + 1023) / 1024;

    k_deg    <<<eb, 256, 0, stream>>>(dst, E, deg);
    k_scanA  <<<nb, 1024, 0, stream>>>(deg, N, incl, bsums);
    k_scanB  <<<1, 1024, 0, stream>>>(bsums, nb, ebs);
    k_scanC  <<<(N+255)/256, 256, 0, stream>>>(incl, ebs, N, rowptr);
    k_scatter<<<eb, 256, 0, stream>>>(src, dst, E, rowptr, fill, esrc);

    // splits
    k_xsplit<<<((N*IN_F/4)+255)/256, 256, 0, stream>>>(x, xh, xl, N*IN_F/4);
    k_wsplit<<<(IN_F*256+255)/256, 256, 0, stream>>>(W1l, w1lh, w1ll, IN_F);
    k_wsplit<<<(IN_F*256+255)/256, 256, 0, stream>>>(W1r, w1rh, w1rl, IN_F);
    k_wsplit<<<(HID*256+255)/256, 256, 0, stream>>>(W2l, w2lh, w2ll, HID);
    k_wsplit<<<(HID*256+255)/256, 256, 0, stream>>>(W2r, w2rh, w2rl, HID);

    // layer 1: A1 = mean1 (split), A2 = x (split) -> h single bf16 plane
    k_aggf<IN_F><<<N, IN_F, 0, stream>>>(x, rowptr, esrc, m1h, m1l);
    dim3 g(2, (N + 127) / 128);
    k_gemm<4, 4, true, true, true><<<g, 256, 0, stream>>>(
        m1h, m1l, IN_F, xh, xl, IN_F,
        w1lh, w1ll, IN_F, w1rh, w1rl, IN_F,
        b1l, bng, bnb, bnm, bnv, N, nullptr, hh);

    // layer 2: A1 = mean2 (split), A2 = h (single plane)
    k_aggh<HID><<<N, HID/2, 0, stream>>>(hh, rowptr, esrc, m2h, m2l);
    k_gemm<8, 8, false, false, false><<<g, 256, 0, stream>>>(
        m2h, m2l, HID, hh, nullptr, HID,
        w2lh, w2ll, HID, w2rh, w2rl, HID,
        b2l, nullptr, nullptr, nullptr, nullptr, N, out, nullptr);

    k_l2norm<<<N, 256, 0, stream>>>(out, N);
}

// Round 6
// 622.125 us; speedup vs baseline: 1.7474x; 1.1239x over previous
//
#include <hip/hip_runtime.h>
#include <cstdint>
#include <cstddef>

typedef unsigned short u16;
typedef __attribute__((ext_vector_type(8))) short short8;
typedef __attribute__((ext_vector_type(4))) float f32x4;

static constexpr int IN_F = 128;
static constexpr int HID  = 256;
#define EPS_BN 1e-5f
#define EPS_L2 1e-12f

__device__ inline float bf2f(u16 a){ return __uint_as_float((unsigned)a << 16); }
// f32 -> bf16 round-to-nearest-even (finite values only here)
__device__ inline u16 f2bf_rne(float v){
    unsigned u = __float_as_uint(v);
    return (u16)((u + 0x7fffu + ((u >> 16) & 1u)) >> 16);
}
// RNE split: hi = RNE(v) (usable standalone), lo = RNE(v - hi)
__device__ inline void bsplit(float v, u16& h, u16& l){
    h = f2bf_rne(v);
    float r = v - bf2f(h);
    l = f2bf_rne(r);
}

// ---------------- CSR build ----------------

__global__ void k_deg(const int* __restrict__ dst, int E, int* __restrict__ deg){
    int i = blockIdx.x*256 + threadIdx.x;
    if (i < E) atomicAdd(&deg[dst[i]], 1);
}

__global__ void k_scanA(const int* __restrict__ deg, int N,
                        int* __restrict__ incl, int* __restrict__ bsums){
    __shared__ int lds[1024];
    int i = blockIdx.x*1024 + threadIdx.x;
    int v = (i < N) ? deg[i] : 0;
    lds[threadIdx.x] = v;
    __syncthreads();
    for (int off = 1; off < 1024; off <<= 1){
        int t = (threadIdx.x >= off) ? lds[threadIdx.x - off] : 0;
        __syncthreads();
        lds[threadIdx.x] += t;
        __syncthreads();
    }
    if (i < N) incl[i] = lds[threadIdx.x];
    if (threadIdx.x == 1023) bsums[blockIdx.x] = lds[1023];
}

__global__ void k_scanB(const int* __restrict__ bsums, int nb, int* __restrict__ ebs){
    __shared__ int lds[1024];
    int t = threadIdx.x;
    int v = (t < nb) ? bsums[t] : 0;
    lds[t] = v;
    __syncthreads();
    for (int off = 1; off < 1024; off <<= 1){
        int u = (t >= off) ? lds[t - off] : 0;
        __syncthreads();
        lds[t] += u;
        __syncthreads();
    }
    ebs[t] = lds[t] - v;   // exclusive
}

__global__ void k_scanC(const int* __restrict__ incl, const int* __restrict__ ebs,
                        int N, int* __restrict__ rowptr){
    int i = blockIdx.x*256 + threadIdx.x;
    if (i < N) rowptr[i+1] = incl[i] + ebs[i >> 10];
    if (i == 0) rowptr[0] = 0;
}

__global__ void k_scatter(const int* __restrict__ src, const int* __restrict__ dst, int E,
                          const int* __restrict__ rowptr, int* __restrict__ fill,
                          int* __restrict__ esrc){
    int i = blockIdx.x*256 + threadIdx.x;
    if (i < E){
        int d = dst[i];
        int pos = rowptr[d] + atomicAdd(&fill[d], 1);
        esrc[pos] = src[i];
    }
}

// ---------------- input / weight split passes ----------------

__global__ void k_xsplit(const float* __restrict__ x, u16* __restrict__ xh,
                         u16* __restrict__ xl, int n4){
    int i = blockIdx.x*256 + threadIdx.x;
    if (i >= n4) return;
    float4 v = *(const float4*)&x[(size_t)i*4];
    ushort4 h, l;
    bsplit(v.x, h.x, l.x); bsplit(v.y, h.y, l.y);
    bsplit(v.z, h.z, l.z); bsplit(v.w, h.w, l.w);
    *(ushort4*)&xh[(size_t)i*4] = h;
    *(ushort4*)&xl[(size_t)i*4] = l;
}

// W [K][256] row-major f32 -> Wt planes [256][K] bf16 hi/lo
__global__ void k_wsplit(const float* __restrict__ W, u16* __restrict__ wth,
                         u16* __restrict__ wtl, int K){
    int i = blockIdx.x*256 + threadIdx.x;
    if (i >= K*256) return;
    int k = i >> 8, c = i & 255;
    u16 h, l; bsplit(W[i], h, l);
    wth[c*K + k] = h;
    wtl[c*K + k] = l;
}

// ---------------- mean aggregation (CSR gather, bf16 source) ----------------
// blockDim == F/2; each thread covers 2 features via ushort2.
// MSPLIT: emit hi/lo planes (layer 1) or single RNE plane (layer 2).

template<int F, bool MSPLIT>
__global__ void k_aggb(const u16* __restrict__ fh,
                       const int* __restrict__ rowptr, const int* __restrict__ esrc,
                       u16* __restrict__ mh, u16* __restrict__ ml){
    int n = blockIdx.x, t = threadIdx.x;       // t in [0, F/2)
    int s = rowptr[n], e = rowptr[n+1];
    float a0 = 0.f, a1 = 0.f;
    for (int j = s; j < e; ++j){
        ushort2 v = *(const ushort2*)&fh[(size_t)esrc[j]*F + 2*t];
        a0 += bf2f(v.x);
        a1 += bf2f(v.y);
    }
    float c = fmaxf((float)(e - s), 1.f);
    a0 /= c; a1 /= c;
    if constexpr (MSPLIT){
        ushort2 h, l;
        bsplit(a0, h.x, l.x);
        bsplit(a1, h.y, l.y);
        *(ushort2*)&mh[(size_t)n*F + 2*t] = h;
        *(ushort2*)&ml[(size_t)n*F + 2*t] = l;
    } else {
        ushort2 h;
        h.x = f2bf_rne(a0); h.y = f2bf_rne(a1);
        *(ushort2*)&mh[(size_t)n*F + 2*t] = h;
    }
}

// ---------------- split-bf16 MFMA dual GEMM, double-buffered 1-barrier pipeline ----
// out = A1@W1 + A2@W2 (+bias, +BN/ReLU). Concat along K: NKB1+NKB2 blocks of 32 k.
// ASPLIT: A operands have hi+lo planes (3-term MFMA) else single plane (2-term).
// B (weights) always split. Tile 128x128, 256 thr = 4 waves (2x2 of 64x64),
// mfma_f32_16x16x32_bf16. LDS 16B-chunk slot = row*4 + (chunk ^ (row&3)).
// Pipeline: loads issued 2 K-steps ahead, LDS write 1 ahead, ONE barrier/step.

template<int NKB1, int NKB2, bool ASPLIT, bool BNRELU, bool WRITE_H>
__global__ __launch_bounds__(256, 2) void k_gemm(
    const u16* __restrict__ A1h, const u16* __restrict__ A1l, int sa1,
    const u16* __restrict__ A2h, const u16* __restrict__ A2l, int sa2,
    const u16* __restrict__ B1h, const u16* __restrict__ B1l, int sb1,
    const u16* __restrict__ B2h, const u16* __restrict__ B2l, int sb2,
    const float* __restrict__ bias,
    const float* __restrict__ bng, const float* __restrict__ bnb,
    const float* __restrict__ bnm, const float* __restrict__ bnv,
    int N, float* __restrict__ outf, u16* __restrict__ outh)
{
    constexpr int ABUF  = ASPLIT ? 1024 : 512;   // uint4 per A region
    constexpr int BUFSZ = ABUF + 1024;           // + B hi/lo
    __shared__ uint4 L[2*BUFSZ];

    const int t    = threadIdx.x;
    const int wave = t >> 6, lane = t & 63;
    const int wr   = (wave >> 1) * 64;
    const int wc   = (wave &  1) * 64;
    const int m0   = blockIdx.y * 128;
    const int c0   = blockIdx.x * 128;

    f32x4 acc[4][4] = {};

    const int r0 = t >> 2,        cc0 = t & 3;
    const int r1 = (t+256) >> 2,  cc1 = (t+256) & 3;
    const int slot0 = r0*4 + (cc0 ^ (r0 & 3));
    const int slot1 = r1*4 + (cc1 ^ (r1 & 3));
    const int ar0 = min(m0 + r0, N-1);
    const int ar1 = min(m0 + r1, N-1);
    const int br0 = c0 + r0, br1 = c0 + r1;

    uint4 sAh0, sAh1, sAl0, sAl1, sBh0, sBh1, sBl0, sBl1;

    auto LOADK = [&](int kb){
        const u16 *pAh, *pAl, *pBh, *pBl; int sA, sB, k0;
        if (kb < NKB1){ pAh=A1h; pAl=A1l; sA=sa1; pBh=B1h; pBl=B1l; sB=sb1; k0 = kb*32; }
        else          { pAh=A2h; pAl=A2l; sA=sa2; pBh=B2h; pBl=B2l; sB=sb2; k0 = (kb-NKB1)*32; }
        sAh0 = *(const uint4*)(pAh + (size_t)ar0*sA + k0 + cc0*8);
        sAh1 = *(const uint4*)(pAh + (size_t)ar1*sA + k0 + cc1*8);
        if constexpr (ASPLIT){
            sAl0 = *(const uint4*)(pAl + (size_t)ar0*sA + k0 + cc0*8);
            sAl1 = *(const uint4*)(pAl + (size_t)ar1*sA + k0 + cc1*8);
        }
        sBh0 = *(const uint4*)(pBh + (size_t)br0*sB + k0 + cc0*8);
        sBh1 = *(const uint4*)(pBh + (size_t)br1*sB + k0 + cc1*8);
        sBl0 = *(const uint4*)(pBl + (size_t)br0*sB + k0 + cc0*8);
        sBl1 = *(const uint4*)(pBl + (size_t)br1*sB + k0 + cc1*8);
    };
    auto STOREK = [&](int buf){
        uint4* Lb = &L[buf*BUFSZ];
        Lb[slot0] = sAh0;  Lb[slot1] = sAh1;
        if constexpr (ASPLIT){ Lb[512+slot0] = sAl0;  Lb[512+slot1] = sAl1; }
        Lb[ABUF+slot0]     = sBh0;  Lb[ABUF+slot1]     = sBh1;
        Lb[ABUF+512+slot0] = sBl0;  Lb[ABUF+512+slot1] = sBl1;
    };

    constexpr int NKB = NKB1 + NKB2;
    LOADK(0);
    STOREK(0);
    LOADK(1);
    __syncthreads();

    const int cl = lane & 15;
    const int cg = lane >> 4;

    #pragma unroll 2
    for (int kb = 0; kb < NKB; ++kb){
        const int cur = kb & 1;
        uint4* Lb = &L[cur*BUFSZ];
        if (kb + 1 < NKB) STOREK(cur ^ 1);   // data(kb+1) -> other buffer
        if (kb + 2 < NKB) LOADK(kb + 2);     // issue loads 2 ahead

        short8 bh[4], bl[4];
        #pragma unroll
        for (int n = 0; n < 4; ++n){
            int col  = wc + n*16 + cl;
            int slot = col*4 + (cg ^ (col & 3));
            bh[n] = *(const short8*)&Lb[ABUF+slot];
            bl[n] = *(const short8*)&Lb[ABUF+512+slot];
        }
        #pragma unroll
        for (int m = 0; m < 4; ++m){
            int row  = wr + m*16 + cl;
            int slot = row*4 + (cg ^ (row & 3));
            short8 ah = *(const short8*)&Lb[slot];
            if constexpr (ASPLIT){
                short8 al = *(const short8*)&Lb[512+slot];
                #pragma unroll
                for (int n = 0; n < 4; ++n){
                    acc[m][n] = __builtin_amdgcn_mfma_f32_16x16x32_bf16(ah, bh[n], acc[m][n], 0,0,0);
                    acc[m][n] = __builtin_amdgcn_mfma_f32_16x16x32_bf16(al, bh[n], acc[m][n], 0,0,0);
                    acc[m][n] = __builtin_amdgcn_mfma_f32_16x16x32_bf16(ah, bl[n], acc[m][n], 0,0,0);
                }
            } else {
                #pragma unroll
                for (int n = 0; n < 4; ++n){
                    acc[m][n] = __builtin_amdgcn_mfma_f32_16x16x32_bf16(ah, bh[n], acc[m][n], 0,0,0);
                    acc[m][n] = __builtin_amdgcn_mfma_f32_16x16x32_bf16(ah, bl[n], acc[m][n], 0,0,0);
                }
            }
        }
        __syncthreads();
    }

    // epilogue: C/D layout col = lane&15, row = (lane>>4)*4 + reg
    const int rg = lane >> 4;
    #pragma unroll
    for (int n = 0; n < 4; ++n){
        int col = c0 + wc + n*16 + cl;
        float bv = bias[col];
        float g=0.f, be=0.f, mm=0.f, rv=0.f;
        if constexpr (BNRELU){
            g = bng[col]; be = bnb[col]; mm = bnm[col];
            rv = rsqrtf(bnv[col] + EPS_BN);
        }
        #pragma unroll
        for (int m = 0; m < 4; ++m){
            #pragma unroll
            for (int i = 0; i < 4; ++i){
                int row = m0 + wr + m*16 + rg*4 + i;
                if (row < N){
                    float v = acc[m][n][i] + bv;
                    if constexpr (BNRELU) v = fmaxf(g*(v - mm)*rv + be, 0.f);
                    if constexpr (WRITE_H){
                        outh[(size_t)row*256 + col] = f2bf_rne(v);
                    } else {
                        outf[(size_t)row*256 + col] = v;
                    }
                }
            }
        }
    }
}

// ---------------- in-place row L2 normalize ----------------

__global__ __launch_bounds__(256) void k_l2norm(float* __restrict__ out, int N){
    int n = blockIdx.x;
    int t = threadIdx.x;
    float v = out[(size_t)n*256 + t];
    float s = v*v;
    #pragma unroll
    for (int off = 32; off; off >>= 1) s += __shfl_xor(s, off, 64);
    __shared__ float ws[4];
    if ((t & 63) == 0) ws[t >> 6] = s;
    __syncthreads();
    s = ws[0] + ws[1] + ws[2] + ws[3];
    float nrm = fmaxf(sqrtf(s), EPS_L2);
    out[(size_t)n*256 + t] = v / nrm;
}

// ---------------- launch ----------------

extern "C" void kernel_launch(void* const* d_in, const int* in_sizes, int n_in,
                              void* d_out, int out_size, void* d_ws, size_t ws_size,
                              hipStream_t stream){
    const float* x   = (const float*)d_in[0];
    const int*   ei  = (const int*)  d_in[1];
    const float* W1l = (const float*)d_in[2];
    const float* b1l = (const float*)d_in[3];
    const float* W1r = (const float*)d_in[4];
    const float* bng = (const float*)d_in[5];
    const float* bnb = (const float*)d_in[6];
    const float* bnm = (const float*)d_in[7];
    const float* bnv = (const float*)d_in[8];
    const float* W2l = (const float*)d_in[9];
    const float* b2l = (const float*)d_in[10];
    const float* W2r = (const float*)d_in[11];
    float* out = (float*)d_out;

    const int N = in_sizes[0] / IN_F;
    const int E = in_sizes[1] / 2;
    const int* src = ei;
    const int* dst = ei + E;

    char* w = (char*)d_ws;
    auto alloc = [&](size_t bytes)->char*{
        char* p = w; w += (bytes + 255) & ~(size_t)255; return p;
    };
    int* deg    = (int*)alloc((size_t)N*4);
    int* fill   = (int*)alloc((size_t)N*4);
    int* incl   = (int*)alloc((size_t)N*4);
    int* rowptr = (int*)alloc((size_t)(N+1)*4);
    int* bsums  = (int*)alloc(1024*4);
    int* ebs    = (int*)alloc(1024*4);
    int* esrc   = (int*)alloc((size_t)E*4);
    // region R: x planes + mean1 planes (contiguous; m2 single plane aliases xh..xl)
    u16* xh  = (u16*)alloc((size_t)N*IN_F*2);   // hi = RNE(x) -> also the gather source
    u16* xl  = (u16*)alloc((size_t)N*IN_F*2);
    u16* m1h = (u16*)alloc((size_t)N*IN_F*2);
    u16* m1l = (u16*)alloc((size_t)N*IN_F*2);
    u16* hh  = (u16*)alloc((size_t)N*HID*2);    // single bf16 plane for h
    u16* w1lh = (u16*)alloc((size_t)IN_F*256*2);
    u16* w1ll = (u16*)alloc((size_t)IN_F*256*2);
    u16* w1rh = (u16*)alloc((size_t)IN_F*256*2);
    u16* w1rl = (u16*)alloc((size_t)IN_F*256*2);
    u16* w2lh = (u16*)alloc((size_t)HID*256*2);
    u16* w2ll = (u16*)alloc((size_t)HID*256*2);
    u16* w2rh = (u16*)alloc((size_t)HID*256*2);
    u16* w2rl = (u16*)alloc((size_t)HID*256*2);
    // m2 single plane aliases xh..xl span (N*256*2 bytes, exact; x dead after gemm1)
    u16* m2 = xh;

    hipMemsetAsync(deg,  0, (size_t)N*4, stream);
    hipMemsetAsync(fill, 0, (size_t)N*4, stream);

    const int eb = (E + 255) / 256;
    const int nb = (N + 1023) / 1024;

    k_deg    <<<eb, 256, 0, stream>>>(dst, E, deg);
    k_scanA  <<<nb, 1024, 0, stream>>>(deg, N, incl, bsums);
    k_scanB  <<<1, 1024, 0, stream>>>(bsums, nb, ebs);
    k_scanC  <<<(N+255)/256, 256, 0, stream>>>(incl, ebs, N, rowptr);
    k_scatter<<<eb, 256, 0, stream>>>(src, dst, E, rowptr, fill, esrc);

    // splits
    k_xsplit<<<((N*IN_F/4)+255)/256, 256, 0, stream>>>(x, xh, xl, N*IN_F/4);
    k_wsplit<<<(IN_F*256+255)/256, 256, 0, stream>>>(W1l, w1lh, w1ll, IN_F);
    k_wsplit<<<(IN_F*256+255)/256, 256, 0, stream>>>(W1r, w1rh, w1rl, IN_F);
    k_wsplit<<<(HID*256+255)/256, 256, 0, stream>>>(W2l, w2lh, w2ll, HID);
    k_wsplit<<<(HID*256+255)/256, 256, 0, stream>>>(W2r, w2rh, w2rl, HID);

    // layer 1: mean1 from RNE-bf16 x plane; A1 = mean1 (split), A2 = x (split)
    k_aggb<IN_F, true><<<N, IN_F/2, 0, stream>>>(xh, rowptr, esrc, m1h, m1l);
    dim3 g(2, (N + 127) / 128);
    k_gemm<4, 4, true, true, true><<<g, 256, 0, stream>>>(
        m1h, m1l, IN_F, xh, xl, IN_F,
        w1lh, w1ll, IN_F, w1rh, w1rl, IN_F,
        b1l, bng, bnb, bnm, bnv, N, nullptr, hh);

    // layer 2: mean2 single bf16 plane; A1 = m2, A2 = h (both single)
    k_aggb<HID, false><<<N, HID/2, 0, stream>>>(hh, rowptr, esrc, m2, nullptr);
    k_gemm<8, 8, false, false, false><<<g, 256, 0, stream>>>(
        m2, nullptr, HID, hh, nullptr, HID,
        w2lh, w2ll, HID, w2rh, w2rl, HID,
        b2l, nullptr, nullptr, nullptr, nullptr, N, out, nullptr);

    k_l2norm<<<N, 256, 0, stream>>>(out, N);
}

// Round 7
// 578.345 us; speedup vs baseline: 1.8796x; 1.0757x over previous
//
#include <hip/hip_runtime.h>
#include <cstdint>
#include <cstddef>

typedef unsigned short u16;
typedef unsigned int u32;
typedef __attribute__((ext_vector_type(8))) short short8;
typedef __attribute__((ext_vector_type(4))) float f32x4;

static constexpr int IN_F = 128;
static constexpr int HID  = 256;
#define EPS_BN 1e-5f
#define EPS_L2 1e-12f

__device__ inline float bf2f(u16 a){ return __uint_as_float((unsigned)a << 16); }
// f32 -> bf16 round-to-nearest-even (finite values only here)
__device__ inline u16 f2bf_rne(float v){
    unsigned u = __float_as_uint(v);
    return (u16)((u + 0x7fffu + ((u >> 16) & 1u)) >> 16);
}
// RNE split: hi = RNE(v) (usable standalone), lo = RNE(v - hi)
__device__ inline void bsplit(float v, u16& h, u16& l){
    h = f2bf_rne(v);
    float r = v - bf2f(h);
    l = f2bf_rne(r);
}
__device__ inline u32 pack2(u16 a, u16 b){ return (u32)a | ((u32)b << 16); }

// ---------------- CSR build ----------------

__global__ void k_deg(const int* __restrict__ dst, int E, int* __restrict__ deg){
    int i = blockIdx.x*256 + threadIdx.x;
    if (i < E) atomicAdd(&deg[dst[i]], 1);
}

__global__ void k_scanA(const int* __restrict__ deg, int N,
                        int* __restrict__ incl, int* __restrict__ bsums){
    __shared__ int lds[1024];
    int i = blockIdx.x*1024 + threadIdx.x;
    int v = (i < N) ? deg[i] : 0;
    lds[threadIdx.x] = v;
    __syncthreads();
    for (int off = 1; off < 1024; off <<= 1){
        int t = (threadIdx.x >= off) ? lds[threadIdx.x - off] : 0;
        __syncthreads();
        lds[threadIdx.x] += t;
        __syncthreads();
    }
    if (i < N) incl[i] = lds[threadIdx.x];
    if (threadIdx.x == 1023) bsums[blockIdx.x] = lds[1023];
}

__global__ void k_scanB(const int* __restrict__ bsums, int nb, int* __restrict__ ebs){
    __shared__ int lds[1024];
    int t = threadIdx.x;
    int v = (t < nb) ? bsums[t] : 0;
    lds[t] = v;
    __syncthreads();
    for (int off = 1; off < 1024; off <<= 1){
        int u = (t >= off) ? lds[t - off] : 0;
        __syncthreads();
        lds[t] += u;
        __syncthreads();
    }
    ebs[t] = lds[t] - v;   // exclusive
}

__global__ void k_scanC(const int* __restrict__ incl, const int* __restrict__ ebs,
                        int N, int* __restrict__ rowptr){
    int i = blockIdx.x*256 + threadIdx.x;
    if (i < N) rowptr[i+1] = incl[i] + ebs[i >> 10];
    if (i == 0) rowptr[0] = 0;
}

__global__ void k_scatter(const int* __restrict__ src, const int* __restrict__ dst, int E,
                          const int* __restrict__ rowptr, int* __restrict__ fill,
                          int* __restrict__ esrc){
    int i = blockIdx.x*256 + threadIdx.x;
    if (i < E){
        int d = dst[i];
        int pos = rowptr[d] + atomicAdd(&fill[d], 1);
        esrc[pos] = src[i];
    }
}

// ---------------- input / weight split passes ----------------

__global__ void k_xsplit(const float* __restrict__ x, u16* __restrict__ xh,
                         u16* __restrict__ xl, int n4){
    int i = blockIdx.x*256 + threadIdx.x;
    if (i >= n4) return;
    float4 v = *(const float4*)&x[(size_t)i*4];
    ushort4 h, l;
    bsplit(v.x, h.x, l.x); bsplit(v.y, h.y, l.y);
    bsplit(v.z, h.z, l.z); bsplit(v.w, h.w, l.w);
    *(ushort4*)&xh[(size_t)i*4] = h;
    *(ushort4*)&xl[(size_t)i*4] = l;
}

// W [K][256] row-major f32 -> Wt planes [256][K] bf16 hi/lo
__global__ void k_wsplit(const float* __restrict__ W, u16* __restrict__ wth,
                         u16* __restrict__ wtl, int K){
    int i = blockIdx.x*256 + threadIdx.x;
    if (i >= K*256) return;
    int k = i >> 8, c = i & 255;
    u16 h, l; bsplit(W[i], h, l);
    wth[c*K + k] = h;
    wtl[c*K + k] = l;
}

// ---------------- mean aggregation (wave-per-node, 16B/lane gather) ----------------
// One wave per node; EPI edges processed concurrently (sub-groups of LPR lanes,
// each lane holds 8 contiguous feats as uint4). shfl_xor tree combines partials.
// MSPLIT: emit hi/lo planes (layer 1) or single RNE plane (layer 2).

template<int F, bool MSPLIT>
__global__ __launch_bounds__(128) void k_aggw(const u16* __restrict__ fh,
    const int* __restrict__ rowptr, const int* __restrict__ esrc,
    u16* __restrict__ mh, u16* __restrict__ ml, int N)
{
    const int n = blockIdx.x*2 + (threadIdx.x >> 6);
    if (n >= N) return;
    const int lane = threadIdx.x & 63;
    constexpr int LPR = (F*2)/16;   // lanes per row: F=256 -> 32, F=128 -> 16
    constexpr int EPI = 64/LPR;     // edges in flight: 2 or 4
    const int sub = lane / LPR;
    const int fo  = (lane % LPR) * 8;
    const int s = rowptr[n], e = rowptr[n+1];

    float a[8] = {};
    for (int j = s + sub; j < e; j += EPI){
        uint4 v = *(const uint4*)(fh + (size_t)esrc[j]*F + fo);
        a[0] += __uint_as_float(v.x << 16); a[1] += __uint_as_float(v.x & 0xffff0000u);
        a[2] += __uint_as_float(v.y << 16); a[3] += __uint_as_float(v.y & 0xffff0000u);
        a[4] += __uint_as_float(v.z << 16); a[5] += __uint_as_float(v.z & 0xffff0000u);
        a[6] += __uint_as_float(v.w << 16); a[7] += __uint_as_float(v.w & 0xffff0000u);
    }
    #pragma unroll
    for (int k = 0; k < 8; ++k){
        if constexpr (EPI == 4) a[k] += __shfl_xor(a[k], 16, 64);
        a[k] += __shfl_xor(a[k], 32, 64);
    }
    const float rc = 1.f / fmaxf((float)(e - s), 1.f);
    #pragma unroll
    for (int k = 0; k < 8; ++k) a[k] *= rc;

    if constexpr (MSPLIT){
        if (sub == 0){
            uint4 o;
            o.x = pack2(f2bf_rne(a[0]), f2bf_rne(a[1]));
            o.y = pack2(f2bf_rne(a[2]), f2bf_rne(a[3]));
            o.z = pack2(f2bf_rne(a[4]), f2bf_rne(a[5]));
            o.w = pack2(f2bf_rne(a[6]), f2bf_rne(a[7]));
            *(uint4*)(mh + (size_t)n*F + fo) = o;
        } else if (sub == 1){
            u16 lo[8];
            #pragma unroll
            for (int k = 0; k < 8; ++k){
                u16 hh_, ll_; bsplit(a[k], hh_, ll_);
                lo[k] = ll_;
            }
            uint4 o;
            o.x = pack2(lo[0], lo[1]);
            o.y = pack2(lo[2], lo[3]);
            o.z = pack2(lo[4], lo[5]);
            o.w = pack2(lo[6], lo[7]);
            *(uint4*)(ml + (size_t)n*F + fo) = o;
        }
    } else {
        if (sub == 0){
            uint4 o;
            o.x = pack2(f2bf_rne(a[0]), f2bf_rne(a[1]));
            o.y = pack2(f2bf_rne(a[2]), f2bf_rne(a[3]));
            o.z = pack2(f2bf_rne(a[4]), f2bf_rne(a[5]));
            o.w = pack2(f2bf_rne(a[6]), f2bf_rne(a[7]));
            *(uint4*)(mh + (size_t)n*F + fo) = o;
        }
    }
}

// ---------------- split-bf16 MFMA dual GEMM, double-buffered 1-barrier pipeline ----
// out = A1@W1 + A2@W2 (+bias, +BN/ReLU). Concat along K: NKB1+NKB2 blocks of 32 k.
// ASPLIT: A operands have hi+lo planes (3-term MFMA) else single plane (2-term).
// B (weights) always split. Tile 128x128, 256 thr = 4 waves (2x2 of 64x64),
// mfma_f32_16x16x32_bf16. LDS 16B-chunk slot = row*4 + (chunk ^ (row&3)).
// Pipeline: loads issued 2 K-steps ahead, LDS write 1 ahead, ONE barrier/step.

template<int NKB1, int NKB2, bool ASPLIT, bool BNRELU, bool WRITE_H>
__global__ __launch_bounds__(256, 2) void k_gemm(
    const u16* __restrict__ A1h, const u16* __restrict__ A1l, int sa1,
    const u16* __restrict__ A2h, const u16* __restrict__ A2l, int sa2,
    const u16* __restrict__ B1h, const u16* __restrict__ B1l, int sb1,
    const u16* __restrict__ B2h, const u16* __restrict__ B2l, int sb2,
    const float* __restrict__ bias,
    const float* __restrict__ bng, const float* __restrict__ bnb,
    const float* __restrict__ bnm, const float* __restrict__ bnv,
    int N, float* __restrict__ outf, u16* __restrict__ outh)
{
    constexpr int ABUF  = ASPLIT ? 1024 : 512;   // uint4 per A region
    constexpr int BUFSZ = ABUF + 1024;           // + B hi/lo
    __shared__ uint4 L[2*BUFSZ];

    const int t    = threadIdx.x;
    const int wave = t >> 6, lane = t & 63;
    const int wr   = (wave >> 1) * 64;
    const int wc   = (wave &  1) * 64;
    const int m0   = blockIdx.y * 128;
    const int c0   = blockIdx.x * 128;

    f32x4 acc[4][4] = {};

    const int r0 = t >> 2,        cc0 = t & 3;
    const int r1 = (t+256) >> 2,  cc1 = (t+256) & 3;
    const int slot0 = r0*4 + (cc0 ^ (r0 & 3));
    const int slot1 = r1*4 + (cc1 ^ (r1 & 3));
    const int ar0 = min(m0 + r0, N-1);
    const int ar1 = min(m0 + r1, N-1);
    const int br0 = c0 + r0, br1 = c0 + r1;

    uint4 sAh0, sAh1, sAl0, sAl1, sBh0, sBh1, sBl0, sBl1;

    auto LOADK = [&](int kb){
        const u16 *pAh, *pAl, *pBh, *pBl; int sA, sB, k0;
        if (kb < NKB1){ pAh=A1h; pAl=A1l; sA=sa1; pBh=B1h; pBl=B1l; sB=sb1; k0 = kb*32; }
        else          { pAh=A2h; pAl=A2l; sA=sa2; pBh=B2h; pBl=B2l; sB=sb2; k0 = (kb-NKB1)*32; }
        sAh0 = *(const uint4*)(pAh + (size_t)ar0*sA + k0 + cc0*8);
        sAh1 = *(const uint4*)(pAh + (size_t)ar1*sA + k0 + cc1*8);
        if constexpr (ASPLIT){
            sAl0 = *(const uint4*)(pAl + (size_t)ar0*sA + k0 + cc0*8);
            sAl1 = *(const uint4*)(pAl + (size_t)ar1*sA + k0 + cc1*8);
        }
        sBh0 = *(const uint4*)(pBh + (size_t)br0*sB + k0 + cc0*8);
        sBh1 = *(const uint4*)(pBh + (size_t)br1*sB + k0 + cc1*8);
        sBl0 = *(const uint4*)(pBl + (size_t)br0*sB + k0 + cc0*8);
        sBl1 = *(const uint4*)(pBl + (size_t)br1*sB + k0 + cc1*8);
    };
    auto STOREK = [&](int buf){
        uint4* Lb = &L[buf*BUFSZ];
        Lb[slot0] = sAh0;  Lb[slot1] = sAh1;
        if constexpr (ASPLIT){ Lb[512+slot0] = sAl0;  Lb[512+slot1] = sAl1; }
        Lb[ABUF+slot0]     = sBh0;  Lb[ABUF+slot1]     = sBh1;
        Lb[ABUF+512+slot0] = sBl0;  Lb[ABUF+512+slot1] = sBl1;
    };

    constexpr int NKB = NKB1 + NKB2;
    LOADK(0);
    STOREK(0);
    LOADK(1);
    __syncthreads();

    const int cl = lane & 15;
    const int cg = lane >> 4;

    #pragma unroll 2
    for (int kb = 0; kb < NKB; ++kb){
        const int cur = kb & 1;
        uint4* Lb = &L[cur*BUFSZ];
        if (kb + 1 < NKB) STOREK(cur ^ 1);   // data(kb+1) -> other buffer
        if (kb + 2 < NKB) LOADK(kb + 2);     // issue loads 2 ahead

        short8 bh[4], bl[4];
        #pragma unroll
        for (int n = 0; n < 4; ++n){
            int col  = wc + n*16 + cl;
            int slot = col*4 + (cg ^ (col & 3));
            bh[n] = *(const short8*)&Lb[ABUF+slot];
            bl[n] = *(const short8*)&Lb[ABUF+512+slot];
        }
        #pragma unroll
        for (int m = 0; m < 4; ++m){
            int row  = wr + m*16 + cl;
            int slot = row*4 + (cg ^ (row & 3));
            short8 ah = *(const short8*)&Lb[slot];
            if constexpr (ASPLIT){
                short8 al = *(const short8*)&Lb[512+slot];
                #pragma unroll
                for (int n = 0; n < 4; ++n){
                    acc[m][n] = __builtin_amdgcn_mfma_f32_16x16x32_bf16(ah, bh[n], acc[m][n], 0,0,0);
                    acc[m][n] = __builtin_amdgcn_mfma_f32_16x16x32_bf16(al, bh[n], acc[m][n], 0,0,0);
                    acc[m][n] = __builtin_amdgcn_mfma_f32_16x16x32_bf16(ah, bl[n], acc[m][n], 0,0,0);
                }
            } else {
                #pragma unroll
                for (int n = 0; n < 4; ++n){
                    acc[m][n] = __builtin_amdgcn_mfma_f32_16x16x32_bf16(ah, bh[n], acc[m][n], 0,0,0);
                    acc[m][n] = __builtin_amdgcn_mfma_f32_16x16x32_bf16(ah, bl[n], acc[m][n], 0,0,0);
                }
            }
        }
        __syncthreads();
    }

    // epilogue: C/D layout col = lane&15, row = (lane>>4)*4 + reg
    const int rg = lane >> 4;
    #pragma unroll
    for (int n = 0; n < 4; ++n){
        int col = c0 + wc + n*16 + cl;
        float bv = bias[col];
        float g=0.f, be=0.f, mm=0.f, rv=0.f;
        if constexpr (BNRELU){
            g = bng[col]; be = bnb[col]; mm = bnm[col];
            rv = rsqrtf(bnv[col] + EPS_BN);
        }
        #pragma unroll
        for (int m = 0; m < 4; ++m){
            #pragma unroll
            for (int i = 0; i < 4; ++i){
                int row = m0 + wr + m*16 + rg*4 + i;
                if (row < N){
                    float v = acc[m][n][i] + bv;
                    if constexpr (BNRELU) v = fmaxf(g*(v - mm)*rv + be, 0.f);
                    if constexpr (WRITE_H){
                        outh[(size_t)row*256 + col] = f2bf_rne(v);
                    } else {
                        outf[(size_t)row*256 + col] = v;
                    }
                }
            }
        }
    }
}

// ---------------- in-place row L2 normalize ----------------

__global__ __launch_bounds__(256) void k_l2norm(float* __restrict__ out, int N){
    int n = blockIdx.x;
    int t = threadIdx.x;
    float v = out[(size_t)n*256 + t];
    float s = v*v;
    #pragma unroll
    for (int off = 32; off; off >>= 1) s += __shfl_xor(s, off, 64);
    __shared__ float ws[4];
    if ((t & 63) == 0) ws[t >> 6] = s;
    __syncthreads();
    s = ws[0] + ws[1] + ws[2] + ws[3];
    float nrm = fmaxf(sqrtf(s), EPS_L2);
    out[(size_t)n*256 + t] = v / nrm;
}

// ---------------- launch ----------------

extern "C" void kernel_launch(void* const* d_in, const int* in_sizes, int n_in,
                              void* d_out, int out_size, void* d_ws, size_t ws_size,
                              hipStream_t stream){
    const float* x   = (const float*)d_in[0];
    const int*   ei  = (const int*)  d_in[1];
    const float* W1l = (const float*)d_in[2];
    const float* b1l = (const float*)d_in[3];
    const float* W1r = (const float*)d_in[4];
    const float* bng = (const float*)d_in[5];
    const float* bnb = (const float*)d_in[6];
    const float* bnm = (const float*)d_in[7];
    const float* bnv = (const float*)d_in[8];
    const float* W2l = (const float*)d_in[9];
    const float* b2l = (const float*)d_in[10];
    const float* W2r = (const float*)d_in[11];
    float* out = (float*)d_out;

    const int N = in_sizes[0] / IN_F;
    const int E = in_sizes[1] / 2;
    const int* src = ei;
    const int* dst = ei + E;

    char* w = (char*)d_ws;
    auto alloc = [&](size_t bytes)->char*{
        char* p = w; w += (bytes + 255) & ~(size_t)255; return p;
    };
    int* deg    = (int*)alloc((size_t)N*4);
    int* fill   = (int*)alloc((size_t)N*4);
    int* incl   = (int*)alloc((size_t)N*4);
    int* rowptr = (int*)alloc((size_t)(N+1)*4);
    int* bsums  = (int*)alloc(1024*4);
    int* ebs    = (int*)alloc(1024*4);
    int* esrc   = (int*)alloc((size_t)E*4);
    // region R: x planes + mean1 planes (contiguous; m2 single plane aliases xh..xl)
    u16* xh  = (u16*)alloc((size_t)N*IN_F*2);   // hi = RNE(x) -> also the gather source
    u16* xl  = (u16*)alloc((size_t)N*IN_F*2);
    u16* m1h = (u16*)alloc((size_t)N*IN_F*2);
    u16* m1l = (u16*)alloc((size_t)N*IN_F*2);
    u16* hh  = (u16*)alloc((size_t)N*HID*2);    // single bf16 plane for h
    u16* w1lh = (u16*)alloc((size_t)IN_F*256*2);
    u16* w1ll = (u16*)alloc((size_t)IN_F*256*2);
    u16* w1rh = (u16*)alloc((size_t)IN_F*256*2);
    u16* w1rl = (u16*)alloc((size_t)IN_F*256*2);
    u16* w2lh = (u16*)alloc((size_t)HID*256*2);
    u16* w2ll = (u16*)alloc((size_t)HID*256*2);
    u16* w2rh = (u16*)alloc((size_t)HID*256*2);
    u16* w2rl = (u16*)alloc((size_t)HID*256*2);
    // m2 single plane aliases xh..xl span (N*256*2 bytes, exact; x dead after gemm1)
    u16* m2 = xh;

    hipMemsetAsync(deg,  0, (size_t)N*4, stream);
    hipMemsetAsync(fill, 0, (size_t)N*4, stream);

    const int eb = (E + 255) / 256;
    const int nb = (N + 1023) / 1024;

    k_deg    <<<eb, 256, 0, stream>>>(dst, E, deg);
    k_scanA  <<<nb, 1024, 0, stream>>>(deg, N, incl, bsums);
    k_scanB  <<<1, 1024, 0, stream>>>(bsums, nb, ebs);
    k_scanC  <<<(N+255)/256, 256, 0, stream>>>(incl, ebs, N, rowptr);
    k_scatter<<<eb, 256, 0, stream>>>(src, dst, E, rowptr, fill, esrc);

    // splits
    k_xsplit<<<((N*IN_F/4)+255)/256, 256, 0, stream>>>(x, xh, xl, N*IN_F/4);
    k_wsplit<<<(IN_F*256+255)/256, 256, 0, stream>>>(W1l, w1lh, w1ll, IN_F);
    k_wsplit<<<(IN_F*256+255)/256, 256, 0, stream>>>(W1r, w1rh, w1rl, IN_F);
    k_wsplit<<<(HID*256+255)/256, 256, 0, stream>>>(W2l, w2lh, w2ll, HID);
    k_wsplit<<<(HID*256+255)/256, 256, 0, stream>>>(W2r, w2rh, w2rl, HID);

    // layer 1: mean1 from RNE-bf16 x plane; A1 = mean1 (split), A2 = x (split)
    k_aggw<IN_F, true><<<(N+1)/2, 128, 0, stream>>>(xh, rowptr, esrc, m1h, m1l, N);
    dim3 g(2, (N + 127) / 128);
    k_gemm<4, 4, true, true, true><<<g, 256, 0, stream>>>(
        m1h, m1l, IN_F, xh, xl, IN_F,
        w1lh, w1ll, IN_F, w1rh, w1rl, IN_F,
        b1l, bng, bnb, bnm, bnv, N, nullptr, hh);

    // layer 2: mean2 single bf16 plane; A1 = m2, A2 = h (both single)
    k_aggw<HID, false><<<(N+1)/2, 128, 0, stream>>>(hh, rowptr, esrc, m2, nullptr, N);
    k_gemm<8, 8, false, false, false><<<g, 256, 0, stream>>>(
        m2, nullptr, HID, hh, nullptr, HID,
        w2lh, w2ll, HID, w2rh, w2rl, HID,
        b2l, nullptr, nullptr, nullptr, nullptr, N, out, nullptr);

    k_l2norm<<<N, 256, 0, stream>>>(out, N);
}

// Round 8
// 550.338 us; speedup vs baseline: 1.9753x; 1.0509x over previous
//
#include <hip/hip_runtime.h>
#include <cstdint>
#include <cstddef>

typedef unsigned short u16;
typedef unsigned int u32;
typedef __attribute__((ext_vector_type(8))) short short8;
typedef __attribute__((ext_vector_type(4))) float f32x4;

static constexpr int IN_F = 128;
static constexpr int HID  = 256;
#define EPS_BN 1e-5f
#define EPS_L2 1e-12f

__device__ inline float bf2f(u16 a){ return __uint_as_float((unsigned)a << 16); }
// f32 -> bf16 round-to-nearest-even (finite values only here)
__device__ inline u16 f2bf_rne(float v){
    unsigned u = __float_as_uint(v);
    return (u16)((u + 0x7fffu + ((u >> 16) & 1u)) >> 16);
}
// RNE split: hi = RNE(v), lo = RNE(v - hi)
__device__ inline void bsplit(float v, u16& h, u16& l){
    h = f2bf_rne(v);
    float r = v - bf2f(h);
    l = f2bf_rne(r);
}
__device__ inline u32 pack2(u16 a, u16 b){ return (u32)a | ((u32)b << 16); }

// ---------------- CSR build ----------------

__global__ void k_deg(const int* __restrict__ dst, int E, int* __restrict__ deg){
    int i = blockIdx.x*256 + threadIdx.x;
    if (i < E) atomicAdd(&deg[dst[i]], 1);
}

__global__ void k_scanA(const int* __restrict__ deg, int N,
                        int* __restrict__ incl, int* __restrict__ bsums){
    __shared__ int lds[1024];
    int i = blockIdx.x*1024 + threadIdx.x;
    int v = (i < N) ? deg[i] : 0;
    lds[threadIdx.x] = v;
    __syncthreads();
    for (int off = 1; off < 1024; off <<= 1){
        int t = (threadIdx.x >= off) ? lds[threadIdx.x - off] : 0;
        __syncthreads();
        lds[threadIdx.x] += t;
        __syncthreads();
    }
    if (i < N) incl[i] = lds[threadIdx.x];
    if (threadIdx.x == 1023) bsums[blockIdx.x] = lds[1023];
}

__global__ void k_scanB(const int* __restrict__ bsums, int nb, int* __restrict__ ebs){
    __shared__ int lds[1024];
    int t = threadIdx.x;
    int v = (t < nb) ? bsums[t] : 0;
    lds[t] = v;
    __syncthreads();
    for (int off = 1; off < 1024; off <<= 1){
        int u = (t >= off) ? lds[t - off] : 0;
        __syncthreads();
        lds[t] += u;
        __syncthreads();
    }
    ebs[t] = lds[t] - v;   // exclusive
}

__global__ void k_scanC(const int* __restrict__ incl, const int* __restrict__ ebs,
                        int N, int* __restrict__ rowptr){
    int i = blockIdx.x*256 + threadIdx.x;
    if (i < N) rowptr[i+1] = incl[i] + ebs[i >> 10];
    if (i == 0) rowptr[0] = 0;
}

__global__ void k_scatter(const int* __restrict__ src, const int* __restrict__ dst, int E,
                          const int* __restrict__ rowptr, int* __restrict__ fill,
                          int* __restrict__ esrc){
    int i = blockIdx.x*256 + threadIdx.x;
    if (i < E){
        int d = dst[i];
        int pos = rowptr[d] + atomicAdd(&fill[d], 1);
        esrc[pos] = src[i];
    }
}

// ---------------- input / weight conversion ----------------

// x f32 -> single RNE bf16 plane
__global__ void k_xbf(const float* __restrict__ x, u16* __restrict__ xh, int n4){
    int i = blockIdx.x*256 + threadIdx.x;
    if (i >= n4) return;
    float4 v = *(const float4*)&x[(size_t)i*4];
    ushort4 h;
    h.x = f2bf_rne(v.x); h.y = f2bf_rne(v.y);
    h.z = f2bf_rne(v.z); h.w = f2bf_rne(v.w);
    *(ushort4*)&xh[(size_t)i*4] = h;
}

// W [K][256] row-major f32 -> Wt planes [256][K] bf16 hi/lo
__global__ void k_wsplit(const float* __restrict__ W, u16* __restrict__ wth,
                         u16* __restrict__ wtl, int K){
    int i = blockIdx.x*256 + threadIdx.x;
    if (i >= K*256) return;
    int k = i >> 8, c = i & 255;
    u16 h, l; bsplit(W[i], h, l);
    wth[c*K + k] = h;
    wtl[c*K + k] = l;
}

// ---------------- mean aggregation (wave-per-node, 16B/lane gather) ----------------
// One wave per node; EPI edges in flight (sub-groups of LPR lanes, each lane holds
// 8 contiguous feats as uint4). shfl_xor tree combines partials. Output: RNE bf16.

template<int F>
__global__ __launch_bounds__(128) void k_aggw(const u16* __restrict__ fh,
    const int* __restrict__ rowptr, const int* __restrict__ esrc,
    u16* __restrict__ mh, int N)
{
    const int n = blockIdx.x*2 + (threadIdx.x >> 6);
    if (n >= N) return;
    const int lane = threadIdx.x & 63;
    constexpr int LPR = (F*2)/16;   // lanes per row: F=256 -> 32, F=128 -> 16
    constexpr int EPI = 64/LPR;     // edges in flight: 2 or 4
    const int sub = lane / LPR;
    const int fo  = (lane % LPR) * 8;
    const int s = rowptr[n], e = rowptr[n+1];

    float a[8] = {};
    for (int j = s + sub; j < e; j += EPI){
        uint4 v = *(const uint4*)(fh + (size_t)esrc[j]*F + fo);
        a[0] += __uint_as_float(v.x << 16); a[1] += __uint_as_float(v.x & 0xffff0000u);
        a[2] += __uint_as_float(v.y << 16); a[3] += __uint_as_float(v.y & 0xffff0000u);
        a[4] += __uint_as_float(v.z << 16); a[5] += __uint_as_float(v.z & 0xffff0000u);
        a[6] += __uint_as_float(v.w << 16); a[7] += __uint_as_float(v.w & 0xffff0000u);
    }
    #pragma unroll
    for (int k = 0; k < 8; ++k){
        if constexpr (EPI == 4) a[k] += __shfl_xor(a[k], 16, 64);
        a[k] += __shfl_xor(a[k], 32, 64);
    }
    if (sub == 0){
        const float rc = 1.f / fmaxf((float)(e - s), 1.f);
        uint4 o;
        o.x = pack2(f2bf_rne(a[0]*rc), f2bf_rne(a[1]*rc));
        o.y = pack2(f2bf_rne(a[2]*rc), f2bf_rne(a[3]*rc));
        o.z = pack2(f2bf_rne(a[4]*rc), f2bf_rne(a[5]*rc));
        o.w = pack2(f2bf_rne(a[6]*rc), f2bf_rne(a[7]*rc));
        *(uint4*)(mh + (size_t)n*F + fo) = o;
    }
}

// ---------------- bf16 MFMA dual GEMM, double-buffered 1-barrier pipeline -------
// out = A1@W1 + A2@W2 (+bias, +BN/ReLU). Concat along K: NKB1+NKB2 blocks of 32 k.
// A operands: single bf16 plane. B (weights): hi+lo planes (2-term MFMA).
// Tile 128x128, 256 thr = 4 waves (2x2 of 64x64), mfma_f32_16x16x32_bf16.
// LDS 16B-chunk slot = row*4 + (chunk ^ (row&3)). Loads 2 K-steps ahead, LDS
// write 1 ahead, ONE barrier/step. 1-D grid + bijective XCD swizzle (m204):
// consecutive wgid = same-row col-tile pairs -> A-tile L2-hot within an XCD.

template<int NKB1, int NKB2, bool BNRELU, bool WRITE_H>
__global__ __launch_bounds__(256, 3) void k_gemm(
    const u16* __restrict__ A1, int sa1,
    const u16* __restrict__ A2, int sa2,
    const u16* __restrict__ B1h, const u16* __restrict__ B1l, int sb1,
    const u16* __restrict__ B2h, const u16* __restrict__ B2l, int sb2,
    const float* __restrict__ bias,
    const float* __restrict__ bng, const float* __restrict__ bnb,
    const float* __restrict__ bnm, const float* __restrict__ bnv,
    int N, float* __restrict__ outf, u16* __restrict__ outh)
{
    constexpr int ABUF  = 512;            // uint4 for A tile
    constexpr int BUFSZ = ABUF + 1024;    // + B hi/lo
    __shared__ uint4 L[2*BUFSZ];          // 49152 B -> 3 blocks/CU

    // bijective XCD swizzle (8 XCDs)
    const int nwg = gridDim.x;
    const int q = nwg >> 3, r = nwg & 7;
    {
    }
    const int orig = blockIdx.x;
    const int xcd = orig & 7, pos = orig >> 3;
    const int wgid = (xcd < r ? xcd*(q+1) : r*(q+1) + (xcd-r)*q) + pos;
    const int c0 = (wgid & 1) * 128;
    const int m0 = (wgid >> 1) * 128;

    const int t    = threadIdx.x;
    const int wave = t >> 6, lane = t & 63;
    const int wr   = (wave >> 1) * 64;
    const int wc   = (wave &  1) * 64;

    f32x4 acc[4][4] = {};

    const int r0 = t >> 2,        cc0 = t & 3;
    const int r1 = (t+256) >> 2,  cc1 = (t+256) & 3;
    const int slot0 = r0*4 + (cc0 ^ (r0 & 3));
    const int slot1 = r1*4 + (cc1 ^ (r1 & 3));
    const int ar0 = min(m0 + r0, N-1);
    const int ar1 = min(m0 + r1, N-1);
    const int br0 = c0 + r0, br1 = c0 + r1;

    uint4 sA0, sA1, sBh0, sBh1, sBl0, sBl1;

    auto LOADK = [&](int kb){
        const u16 *pA, *pBh, *pBl; int sA, sB, k0;
        if (kb < NKB1){ pA=A1; sA=sa1; pBh=B1h; pBl=B1l; sB=sb1; k0 = kb*32; }
        else          { pA=A2; sA=sa2; pBh=B2h; pBl=B2l; sB=sb2; k0 = (kb-NKB1)*32; }
        sA0  = *(const uint4*)(pA  + (size_t)ar0*sA + k0 + cc0*8);
        sA1  = *(const uint4*)(pA  + (size_t)ar1*sA + k0 + cc1*8);
        sBh0 = *(const uint4*)(pBh + (size_t)br0*sB + k0 + cc0*8);
        sBh1 = *(const uint4*)(pBh + (size_t)br1*sB + k0 + cc1*8);
        sBl0 = *(const uint4*)(pBl + (size_t)br0*sB + k0 + cc0*8);
        sBl1 = *(const uint4*)(pBl + (size_t)br1*sB + k0 + cc1*8);
    };
    auto STOREK = [&](int buf){
        uint4* Lb = &L[buf*BUFSZ];
        Lb[slot0] = sA0;  Lb[slot1] = sA1;
        Lb[ABUF+slot0]     = sBh0;  Lb[ABUF+slot1]     = sBh1;
        Lb[ABUF+512+slot0] = sBl0;  Lb[ABUF+512+slot1] = sBl1;
    };

    constexpr int NKB = NKB1 + NKB2;
    LOADK(0);
    STOREK(0);
    LOADK(1);
    __syncthreads();

    const int cl = lane & 15;
    const int cg = lane >> 4;

    #pragma unroll 2
    for (int kb = 0; kb < NKB; ++kb){
        const int cur = kb & 1;
        uint4* Lb = &L[cur*BUFSZ];
        if (kb + 1 < NKB) STOREK(cur ^ 1);   // data(kb+1) -> other buffer
        if (kb + 2 < NKB) LOADK(kb + 2);     // issue loads 2 ahead

        short8 bh[4], bl[4];
        #pragma unroll
        for (int n = 0; n < 4; ++n){
            int col  = wc + n*16 + cl;
            int slot = col*4 + (cg ^ (col & 3));
            bh[n] = *(const short8*)&Lb[ABUF+slot];
            bl[n] = *(const short8*)&Lb[ABUF+512+slot];
        }
        #pragma unroll
        for (int m = 0; m < 4; ++m){
            int row  = wr + m*16 + cl;
            int slot = row*4 + (cg ^ (row & 3));
            short8 ah = *(const short8*)&Lb[slot];
            #pragma unroll
            for (int n = 0; n < 4; ++n){
                acc[m][n] = __builtin_amdgcn_mfma_f32_16x16x32_bf16(ah, bh[n], acc[m][n], 0,0,0);
                acc[m][n] = __builtin_amdgcn_mfma_f32_16x16x32_bf16(ah, bl[n], acc[m][n], 0,0,0);
            }
        }
        __syncthreads();
    }

    // epilogue: C/D layout col = lane&15, row = (lane>>4)*4 + reg
    const int rg = lane >> 4;
    #pragma unroll
    for (int n = 0; n < 4; ++n){
        int col = c0 + wc + n*16 + cl;
        float bv = bias[col];
        float g=0.f, be=0.f, mm=0.f, rv=0.f;
        if constexpr (BNRELU){
            g = bng[col]; be = bnb[col]; mm = bnm[col];
            rv = rsqrtf(bnv[col] + EPS_BN);
        }
        #pragma unroll
        for (int m = 0; m < 4; ++m){
            #pragma unroll
            for (int i = 0; i < 4; ++i){
                int row = m0 + wr + m*16 + rg*4 + i;
                if (row < N){
                    float v = acc[m][n][i] + bv;
                    if constexpr (BNRELU) v = fmaxf(g*(v - mm)*rv + be, 0.f);
                    if constexpr (WRITE_H){
                        outh[(size_t)row*256 + col] = f2bf_rne(v);
                    } else {
                        outf[(size_t)row*256 + col] = v;
                    }
                }
            }
        }
    }
}

// ---------------- in-place row L2 normalize ----------------

__global__ __launch_bounds__(256) void k_l2norm(float* __restrict__ out, int N){
    int n = blockIdx.x;
    int t = threadIdx.x;
    float v = out[(size_t)n*256 + t];
    float s = v*v;
    #pragma unroll
    for (int off = 32; off; off >>= 1) s += __shfl_xor(s, off, 64);
    __shared__ float ws[4];
    if ((t & 63) == 0) ws[t >> 6] = s;
    __syncthreads();
    s = ws[0] + ws[1] + ws[2] + ws[3];
    float nrm = fmaxf(sqrtf(s), EPS_L2);
    out[(size_t)n*256 + t] = v / nrm;
}

// ---------------- launch ----------------

extern "C" void kernel_launch(void* const* d_in, const int* in_sizes, int n_in,
                              void* d_out, int out_size, void* d_ws, size_t ws_size,
                              hipStream_t stream){
    const float* x   = (const float*)d_in[0];
    const int*   ei  = (const int*)  d_in[1];
    const float* W1l = (const float*)d_in[2];
    const float* b1l = (const float*)d_in[3];
    const float* W1r = (const float*)d_in[4];
    const float* bng = (const float*)d_in[5];
    const float* bnb = (const float*)d_in[6];
    const float* bnm = (const float*)d_in[7];
    const float* bnv = (const float*)d_in[8];
    const float* W2l = (const float*)d_in[9];
    const float* b2l = (const float*)d_in[10];
    const float* W2r = (const float*)d_in[11];
    float* out = (float*)d_out;

    const int N = in_sizes[0] / IN_F;
    const int E = in_sizes[1] / 2;
    const int* src = ei;
    const int* dst = ei + E;

    char* w = (char*)d_ws;
    auto alloc = [&](size_t bytes)->char*{
        char* p = w; w += (bytes + 255) & ~(size_t)255; return p;
    };
    int* deg    = (int*)alloc((size_t)N*4);
    int* fill   = (int*)alloc((size_t)N*4);
    int* incl   = (int*)alloc((size_t)N*4);
    int* rowptr = (int*)alloc((size_t)(N+1)*4);
    int* bsums  = (int*)alloc(1024*4);
    int* ebs    = (int*)alloc(1024*4);
    int* esrc   = (int*)alloc((size_t)E*4);
    // region R: xh + m1 contiguous (N*128 u16 each, exact 256-multiples);
    // m2 (N*256 u16) aliases the combined span after x/m1 are dead.
    u16* xh  = (u16*)alloc((size_t)N*IN_F*2);
    u16* m1  = (u16*)alloc((size_t)N*IN_F*2);
    u16* hh  = (u16*)alloc((size_t)N*HID*2);    // single bf16 plane for h
    u16* w1lh = (u16*)alloc((size_t)IN_F*256*2);
    u16* w1ll = (u16*)alloc((size_t)IN_F*256*2);
    u16* w1rh = (u16*)alloc((size_t)IN_F*256*2);
    u16* w1rl = (u16*)alloc((size_t)IN_F*256*2);
    u16* w2lh = (u16*)alloc((size_t)HID*256*2);
    u16* w2ll = (u16*)alloc((size_t)HID*256*2);
    u16* w2rh = (u16*)alloc((size_t)HID*256*2);
    u16* w2rl = (u16*)alloc((size_t)HID*256*2);
    u16* m2 = xh;   // N*256 u16 spans xh..m1 exactly

    hipMemsetAsync(deg,  0, (size_t)N*4, stream);
    hipMemsetAsync(fill, 0, (size_t)N*4, stream);

    const int eb = (E + 255) / 256;
    const int nb = (N + 1023) / 1024;

    k_deg    <<<eb, 256, 0, stream>>>(dst, E, deg);
    k_scanA  <<<nb, 1024, 0, stream>>>(deg, N, incl, bsums);
    k_scanB  <<<1, 1024, 0, stream>>>(bsums, nb, ebs);
    k_scanC  <<<(N+255)/256, 256, 0, stream>>>(incl, ebs, N, rowptr);
    k_scatter<<<eb, 256, 0, stream>>>(src, dst, E, rowptr, fill, esrc);

    // conversions
    k_xbf<<<((N*IN_F/4)+255)/256, 256, 0, stream>>>(x, xh, N*IN_F/4);
    k_wsplit<<<(IN_F*256+255)/256, 256, 0, stream>>>(W1l, w1lh, w1ll, IN_F);
    k_wsplit<<<(IN_F*256+255)/256, 256, 0, stream>>>(W1r, w1rh, w1rl, IN_F);
    k_wsplit<<<(HID*256+255)/256, 256, 0, stream>>>(W2l, w2lh, w2ll, HID);
    k_wsplit<<<(HID*256+255)/256, 256, 0, stream>>>(W2r, w2rh, w2rl, HID);

    const int nrt = (N + 127) / 128;      // row tiles
    const int nwg = nrt * 2;              // x2 column tiles, flattened

    // layer 1: A1 = mean1, A2 = x (both single bf16 planes)
    k_aggw<IN_F><<<(N+1)/2, 128, 0, stream>>>(xh, rowptr, esrc, m1, N);
    k_gemm<4, 4, true, true><<<nwg, 256, 0, stream>>>(
        m1, IN_F, xh, IN_F,
        w1lh, w1ll, IN_F, w1rh, w1rl, IN_F,
        b1l, bng, bnb, bnm, bnv, N, nullptr, hh);

    // layer 2: A1 = mean2, A2 = h (both single bf16 planes)
    k_aggw<HID><<<(N+1)/2, 128, 0, stream>>>(hh, rowptr, esrc, m2, N);
    k_gemm<8, 8, false, false><<<nwg, 256, 0, stream>>>(
        m2, HID, hh, HID,
        w2lh, w2ll, HID, w2rh, w2rl, HID,
        b2l, nullptr, nullptr, nullptr, nullptr, N, out, nullptr);

    k_l2norm<<<N, 256, 0, stream>>>(out, N);
}